// Round 1
// baseline (1333.900 us; speedup 1.0000x reference)
//
#include <hip/hip_runtime.h>
#include <math.h>

// Problem geometry: B=16, C=6, H=W=512. HW = 2^18 elements per (b, field) slab.
#define HWE 262144
#define PI2SQ4 39.478417604357434f   // 4*pi^2

__device__ __forceinline__ void wave_fence() {
  asm volatile("" ::: "memory");
  __builtin_amdgcn_wave_barrier();
}

// One wave (64 lanes) performs a 512-point complex FFT in LDS, in place,
// natural order in -> natural order out. Radix-2 DIT with bit-reversal.
// No __syncthreads: single-wave lockstep + in-order per-wave LDS.
__device__ void wave_fft512(float2* s, int lane, bool inverse) {
  wave_fence();
  // bit-reverse permutation (9 bits); pairs are disjoint, each swapped by the
  // lane owning the smaller index.
#pragma unroll
  for (int k = 0; k < 8; ++k) {
    int i = lane + (k << 6);
    int r = (int)(__brev((unsigned)i) >> 23);
    if (i < r) { float2 a = s[i]; float2 b = s[r]; s[i] = b; s[r] = a; }
  }
  wave_fence();
  for (int st = 0; st < 9; ++st) {
    int half = 1 << st;
#pragma unroll
    for (int k = 0; k < 4; ++k) {
      int bf = lane + (k << 6);
      int j = bf & (half - 1);
      int i0 = ((bf >> st) << (st + 1)) + j;
      int i1 = i0 + half;
      float ang = (inverse ? 6.283185307179586f : -6.283185307179586f) *
                  (float)j / (float)(half << 1);
      float sw, cw;
      __sincosf(ang, &sw, &cw);
      float2 a = s[i0], b = s[i1];
      float tr = b.x * cw - b.y * sw;
      float ti = b.x * sw + b.y * cw;
      s[i0] = make_float2(a.x + tr, a.y + ti);
      s[i1] = make_float2(a.x - tr, a.y - ti);
    }
    wave_fence();
  }
}

// --- schedule scalars: coef[b] = {sqrt(ac[t]), sqrt(1-ac[t]), sqrt(beta[t])}
__global__ void k_coef(const int* __restrict__ t, float* __restrict__ coef,
                       float* __restrict__ norms) {
  if (threadIdx.x < 32) norms[threadIdx.x] = 0.f;
  if (threadIdx.x == 0) {
    const double s = 0.008;
    double prev = cos((0.0 + s) / (1.0 + s) * 1.5707963267948966);
    prev *= prev;
    double running = 1.0;
    for (int i = 0; i < 1000; ++i) {
      double cn = cos(((double)(i + 1) / 1000.0 + s) / (1.0 + s) * 1.5707963267948966);
      cn *= cn;
      double beta = 1.0 - cn / prev;
      if (beta < 0.0) beta = 0.0;
      if (beta > 0.999) beta = 0.999;
      prev = cn;
      running *= (1.0 - beta);
      for (int b = 0; b < 16; ++b) {
        if (t[b] == i) {
          coef[b * 4 + 0] = (float)sqrt(running);
          coef[b * 4 + 1] = (float)sqrt(1.0 - running);
          coef[b * 4 + 2] = (float)sqrt(beta);
        }
      }
    }
  }
}

// --- one Jacobi smoothing step on 2 stacked fields (layout: slab = f*16+b)
__global__ __launch_bounds__(256) void k_smooth(const float* __restrict__ su,
                                                const float* __restrict__ sv,
                                                float* __restrict__ dst) {
  int gid = blockIdx.x * 256 + threadIdx.x;           // [0, 2*B*HW)
  int x = gid & 511, y = (gid >> 9) & 511;
  int slab = gid >> 18;                               // f*16+b
  const float* s = (slab < 16) ? su : sv;
  int base = (slab & 15) << 18;
  int xm = (x + 511) & 511, xp = (x + 1) & 511;
  int ym = (y + 511) & 511, yp = (y + 1) & 511;
  float c = s[base + (y << 9) + x];
  float L = s[base + (y << 9) + xm], R = s[base + (y << 9) + xp];
  float U = s[base + (ym << 9) + x], D = s[base + (yp << 9) + x];
  dst[gid] = c + 0.1f * (L + R + U + D - 4.f * c);
}

// --- sum of squares per slab (32 slabs), atomic partials
__global__ __launch_bounds__(256) void k_sumsq(const float* __restrict__ f,
                                               float* __restrict__ norms) {
  int fb = blockIdx.x >> 6, chunk = blockIdx.x & 63;
  const float* p = f + ((size_t)fb << 18) + ((size_t)chunk << 12);
  float s = 0.f;
  for (int i = threadIdx.x; i < 4096; i += 256) { float v = p[i]; s += v * v; }
  for (int off = 32; off; off >>= 1) s += __shfl_down(s, off, 64);
  __shared__ float part[4];
  if ((threadIdx.x & 63) == 0) part[threadIdx.x >> 6] = s;
  __syncthreads();
  if (threadIdx.x == 0) atomicAdd(&norms[fb], part[0] + part[1] + part[2] + part[3]);
}

#define XTL(cb, i) (sa * x0[(cb) + (i)] + so * ns[(cb) + (i)])

// --- u*, v* (advection/diffusion/pressure-grad + normalized forcing)
__global__ __launch_bounds__(256) void k_star(const float* __restrict__ x0,
    const float* __restrict__ ns, const float* __restrict__ fA,
    const float* __restrict__ coef, const float* __restrict__ norms,
    float* __restrict__ us, float* __restrict__ vs) {
  int gid = blockIdx.x * 256 + threadIdx.x;
  int x = gid & 511, y = (gid >> 9) & 511, b = gid >> 18;
  float sa = coef[b * 4], so = coef[b * 4 + 1], sb = coef[b * 4 + 2];
  int xm = (x + 511) & 511, xp = (x + 1) & 511;
  int ym = (y + 511) & 511, yp = (y + 1) & 511;
  int iC = (y << 9) + x, iXm = (y << 9) + xm, iXp = (y << 9) + xp;
  int iYm = (ym << 9) + x, iYp = (yp << 9) + x;
  int c0 = (b * 6) << 18, c1 = (b * 6 + 1) << 18, c2 = (b * 6 + 2) << 18;
  float u_c = XTL(c0, iC), u_xm = XTL(c0, iXm), u_xp = XTL(c0, iXp);
  float u_ym = XTL(c0, iYm), u_yp = XTL(c0, iYp);
  float v_c = XTL(c1, iC), v_xm = XTL(c1, iXm), v_xp = XTL(c1, iXp);
  float v_ym = XTL(c1, iYm), v_yp = XTL(c1, iYp);
  float p_xm = XTL(c2, iXm), p_xp = XTL(c2, iXp);
  float p_ym = XTL(c2, iYm), p_yp = XTL(c2, iYp);
  float adv_u = u_c * 0.5f * (u_xp - u_xm) + v_c * 0.5f * (u_yp - u_ym);
  float adv_v = u_c * 0.5f * (v_xp - v_xm) + v_c * 0.5f * (v_yp - v_ym);
  float dif_u = 0.001f * (u_xm + u_xp + u_ym + u_yp - 4.f * u_c);
  float dif_v = 0.001f * (v_xm + v_xp + v_ym + v_yp - 4.f * v_c);
  float dpx = 0.5f * (p_xp - p_xm), dpy = 0.5f * (p_yp - p_ym);
  float rnu = 1.f / fmaxf(sqrtf(norms[b]), 1e-12f);
  float rnv = 1.f / fmaxf(sqrtf(norms[16 + b]), 1e-12f);
  int bb = b << 18;
  float fu = fA[bb + iC] * rnu;
  float fv = fA[((16 + b) << 18) + iC] * rnv;
  us[bb + iC] = u_c + 0.01f * (-adv_u + dif_u - dpx) + sb * fu;
  vs[bb + iC] = v_c + 0.01f * (-adv_v + dif_v - dpy) + sb * fv;
}

// --- row FFT of div(u*, v*) computed on the fly (4 rows/block, 1 per wave)
__global__ __launch_bounds__(256) void k_rowfft_div(const float* __restrict__ us,
    const float* __restrict__ vs, float2* __restrict__ spec) {
  __shared__ float2 lds[4][512];
  int wave = threadIdx.x >> 6, lane = threadIdx.x & 63;
  int row = (blockIdx.x << 2) + wave;
  int b = row >> 9, y = row & 511;
  int ym = (y + 511) & 511, yp = (y + 1) & 511;
  const float* ub = us + ((size_t)b << 18);
  const float* vb = vs + ((size_t)b << 18);
#pragma unroll
  for (int k = 0; k < 8; ++k) {
    int xx = lane + (k << 6);
    int xm = (xx + 511) & 511, xp = (xx + 1) & 511;
    float d = 0.5f * (ub[(y << 9) + xp] - ub[(y << 9) + xm]) +
              0.5f * (vb[(yp << 9) + xx] - vb[(ym << 9) + xx]);
    lds[wave][xx] = make_float2(d, 0.f);
  }
  wave_fft512(lds[wave], lane, false);
  float2* o = spec + ((size_t)row << 9);
#pragma unroll
  for (int k = 0; k < 8; ++k) { int xx = lane + (k << 6); o[xx] = lds[wave][xx]; }
}

// --- fused column FFT + Poisson multiplier + column IFFT (8 columns/block)
__global__ __launch_bounds__(256) void k_poisson_mid(float2* __restrict__ spec) {
  __shared__ float2 lds[8][513];
  int b = blockIdx.x >> 6;
  int c0 = (blockIdx.x & 63) << 3;
  float2* sp = spec + ((size_t)b << 18);
  int c = threadIdx.x & 7, yb = threadIdx.x >> 3;
#pragma unroll
  for (int it = 0; it < 16; ++it) {
    int y = yb + (it << 5);
    lds[c][y] = sp[((size_t)y << 9) + c0 + c];
  }
  __syncthreads();
  int wave = threadIdx.x >> 6, lane = threadIdx.x & 63;
  wave_fft512(&lds[wave][0], lane, false);
  wave_fft512(&lds[wave + 4][0], lane, false);
  __syncthreads();
  const float invN2 = 1.0f / 262144.0f;
#pragma unroll
  for (int it = 0; it < 16; ++it) {
    int y = yb + (it << 5);
    int cg = c0 + c;
    float fx = (cg < 256) ? (float)cg : (float)(cg - 512);
    float fy = (y < 256) ? (float)y : (float)(y - 512);
    float k2 = fmaxf(fx * fx + fy * fy, 1e-10f);
    float m = (cg == 0 && y == 0) ? 0.f : (-invN2 / (PI2SQ4 * k2));
    float2 v = lds[c][y];
    lds[c][y] = make_float2(v.x * m, v.y * m);
  }
  __syncthreads();
  wave_fft512(&lds[wave][0], lane, true);
  wave_fft512(&lds[wave + 4][0], lane, true);
  __syncthreads();
#pragma unroll
  for (int it = 0; it < 16; ++it) {
    int y = yb + (it << 5);
    sp[((size_t)y << 9) + c0 + c] = lds[c][y];
  }
}

// --- row IFFT, keep real part (Poisson p_corr)
__global__ __launch_bounds__(256) void k_rowifft_real(const float2* __restrict__ spec,
                                                      float* __restrict__ dst) {
  __shared__ float2 lds[4][512];
  int wave = threadIdx.x >> 6, lane = threadIdx.x & 63;
  int row = (blockIdx.x << 2) + wave;
  const float2* srow = spec + ((size_t)row << 9);
#pragma unroll
  for (int k = 0; k < 8; ++k) { int xx = lane + (k << 6); lds[wave][xx] = srow[xx]; }
  wave_fft512(lds[wave], lane, true);
  float* d = dst + ((size_t)row << 9);
#pragma unroll
  for (int k = 0; k < 8; ++k) { int xx = lane + (k << 6); d[xx] = lds[wave][xx].x; }
}

// --- fluid final outputs (channels 0,1,2)
__global__ __launch_bounds__(256) void k_fluid_out(const float* __restrict__ x0,
    const float* __restrict__ ns, const float* __restrict__ coef,
    const float* __restrict__ us, const float* __restrict__ vs,
    const float* __restrict__ pc, float* __restrict__ out) {
  int gid = blockIdx.x * 256 + threadIdx.x;
  int x = gid & 511, y = (gid >> 9) & 511, b = gid >> 18;
  float sa = coef[b * 4], so = coef[b * 4 + 1];
  int xm = (x + 511) & 511, xp = (x + 1) & 511;
  int ym = (y + 511) & 511, yp = (y + 1) & 511;
  int iC = (y << 9) + x;
  int bb = b << 18;
  float pxm = pc[bb + (y << 9) + xm], pxp = pc[bb + (y << 9) + xp];
  float pym = pc[bb + (ym << 9) + x], pyp = pc[bb + (yp << 9) + x];
  float pcc = pc[bb + iC];
  int c2 = (b * 6 + 2) << 18;
  float p0 = XTL(c2, iC);
  out[((b * 6 + 0) << 18) + iC] = us[bb + iC] - 0.5f * (pxp - pxm);
  out[((b * 6 + 1) << 18) + iC] = vs[bb + iC] - 0.5f * (pyp - pym);
  out[c2 + iC] = p0 + pcc;
}

// --- row FFT of scaled currents Jx, Jy (field from blockIdx)
__global__ __launch_bounds__(256) void k_rowfft_j(const float* __restrict__ jx,
    const float* __restrict__ jy, const float* __restrict__ coef,
    float2* __restrict__ specA, float2* __restrict__ specB) {
  __shared__ float2 lds[4][512];
  int wave = threadIdx.x >> 6, lane = threadIdx.x & 63;
  int fld = blockIdx.x >> 11;
  int row = ((blockIdx.x & 2047) << 2) + wave;
  int b = row >> 9, y = row & 511;
  const float* src = fld ? jy : jx;
  float sb = coef[b * 4 + 2];
  const float* sr = src + ((size_t)b << 18) + ((size_t)y << 9);
#pragma unroll
  for (int k = 0; k < 8; ++k) {
    int xx = lane + (k << 6);
    lds[wave][xx] = make_float2(sr[xx] * sb, 0.f);
  }
  wave_fft512(lds[wave], lane, false);
  float2* o = (fld ? specB : specA) + ((size_t)row << 9);
#pragma unroll
  for (int k = 0; k < 8; ++k) { int xx = lane + (k << 6); o[xx] = lds[wave][xx]; }
}

// --- fused column FFT + Helmholtz projection + column IFFT (4 cols, 2 fields)
__global__ __launch_bounds__(256) void k_project_mid(float2* __restrict__ sx,
                                                     float2* __restrict__ sy) {
  __shared__ float2 lds[2][4][513];
  int b = blockIdx.x >> 7;
  int c0 = (blockIdx.x & 127) << 2;
  float2* spx = sx + ((size_t)b << 18);
  float2* spy = sy + ((size_t)b << 18);
  {
    int c = threadIdx.x & 3, f = (threadIdx.x >> 2) & 1, yb = threadIdx.x >> 3;
    float2* sp = f ? spy : spx;
#pragma unroll
    for (int it = 0; it < 16; ++it) {
      int y = yb + (it << 5);
      lds[f][c][y] = sp[((size_t)y << 9) + c0 + c];
    }
  }
  __syncthreads();
  int wave = threadIdx.x >> 6, lane = threadIdx.x & 63;
  wave_fft512(&lds[0][wave][0], lane, false);
  wave_fft512(&lds[1][wave][0], lane, false);
  __syncthreads();
  const float invN2 = 1.0f / 262144.0f;
  {
    int c = threadIdx.x & 3, yb = threadIdx.x >> 2;  // 64 row-groups
    int cg = c0 + c;
    float fx = (cg < 256) ? (float)cg : (float)(cg - 512);
#pragma unroll
    for (int it = 0; it < 8; ++it) {
      int y = yb + (it << 6);
      float fy = (y < 256) ? (float)y : (float)(y - 512);
      float k2 = fmaxf(fx * fx + fy * fy, 1e-10f);
      float inv = 1.0f / k2;
      float2 Jx = lds[0][c][y], Jy = lds[1][c][y];
      float Dre = fx * Jx.x + fy * Jy.x;
      float Dim = fx * Jx.y + fy * Jy.y;
      lds[0][c][y] = make_float2((Jx.x - fx * Dre * inv) * invN2,
                                 (Jx.y - fx * Dim * inv) * invN2);
      lds[1][c][y] = make_float2((Jy.x - fy * Dre * inv) * invN2,
                                 (Jy.y - fy * Dim * inv) * invN2);
    }
  }
  __syncthreads();
  wave_fft512(&lds[0][wave][0], lane, true);
  wave_fft512(&lds[1][wave][0], lane, true);
  __syncthreads();
  {
    int c = threadIdx.x & 3, f = (threadIdx.x >> 2) & 1, yb = threadIdx.x >> 3;
    float2* sp = f ? spy : spx;
#pragma unroll
    for (int it = 0; it < 16; ++it) {
      int y = yb + (it << 5);
      sp[((size_t)y << 9) + c0 + c] = lds[f][c][y];
    }
  }
}

// --- row IFFT of both projected currents, keep real part
__global__ __launch_bounds__(256) void k_rowifft_real2(const float2* __restrict__ sA,
    const float2* __restrict__ sB, float* __restrict__ dst) {
  __shared__ float2 lds[4][512];
  int wave = threadIdx.x >> 6, lane = threadIdx.x & 63;
  int fld = blockIdx.x >> 11;
  int row = ((blockIdx.x & 2047) << 2) + wave;
  const float2* srow = (fld ? sB : sA) + ((size_t)row << 9);
#pragma unroll
  for (int k = 0; k < 8; ++k) { int xx = lane + (k << 6); lds[wave][xx] = srow[xx]; }
  wave_fft512(lds[wave], lane, true);
  float* d = dst + ((size_t)fld << 22) + ((size_t)row << 9);
#pragma unroll
  for (int k = 0; k < 8; ++k) { int xx = lane + (k << 6); d[xx] = lds[wave][xx].x; }
}

// --- Bz_new (channel 5)
__global__ __launch_bounds__(256) void k_em_bz(const float* __restrict__ x0,
    const float* __restrict__ ns, const float* __restrict__ coef,
    float* __restrict__ out) {
  int gid = blockIdx.x * 256 + threadIdx.x;
  int x = gid & 511, y = (gid >> 9) & 511, b = gid >> 18;
  float sa = coef[b * 4], so = coef[b * 4 + 1];
  int xm = (x + 511) & 511, xp = (x + 1) & 511;
  int ym = (y + 511) & 511, yp = (y + 1) & 511;
  int iC = (y << 9) + x;
  int c3 = (b * 6 + 3) << 18, c4 = (b * 6 + 4) << 18, c5 = (b * 6 + 5) << 18;
  float ex_ym = XTL(c3, (ym << 9) + x), ex_yp = XTL(c3, (yp << 9) + x);
  float ey_xm = XTL(c4, (y << 9) + xm), ey_xp = XTL(c4, (y << 9) + xp);
  float bz = XTL(c5, iC);
  float curl = 0.5f * (ey_xp - ey_xm) - 0.5f * (ex_yp - ex_ym);
  out[c5 + iC] = bz - 0.01f * curl;   // DT/MU = 0.01
}

// --- Ex_new, Ey_new (channels 3,4) reading Bz_new from out
__global__ __launch_bounds__(256) void k_em_exy(const float* __restrict__ x0,
    const float* __restrict__ ns, const float* __restrict__ coef,
    const float* __restrict__ jpx, const float* __restrict__ jpy,
    float* __restrict__ out) {
  int gid = blockIdx.x * 256 + threadIdx.x;
  int x = gid & 511, y = (gid >> 9) & 511, b = gid >> 18;
  float sa = coef[b * 4], so = coef[b * 4 + 1];
  int xm = (x + 511) & 511, xp = (x + 1) & 511;
  int ym = (y + 511) & 511, yp = (y + 1) & 511;
  int iC = (y << 9) + x;
  int c3 = (b * 6 + 3) << 18, c4 = (b * 6 + 4) << 18, c5 = (b * 6 + 5) << 18;
  const float* bzn = out + c5;
  float ddyB = 0.5f * (bzn[(yp << 9) + x] - bzn[(ym << 9) + x]);
  float ddxB = 0.5f * (bzn[(y << 9) + xp] - bzn[(y << 9) + xm]);
  float ex = XTL(c3, iC);
  float ey = XTL(c4, iC);
  int bb = b << 18;
  out[c3 + iC] = ex + 0.01f * ddyB - 0.01f * jpx[bb + iC];  // DT/EPS = 0.01
  out[c4 + iC] = ey - 0.01f * ddxB - 0.01f * jpy[bb + iC];
}

extern "C" void kernel_launch(void* const* d_in, const int* in_sizes, int n_in,
                              void* d_out, int out_size, void* d_ws, size_t ws_size,
                              hipStream_t stream) {
  const float* x0    = (const float*)d_in[0];
  const float* noise = (const float*)d_in[1];
  const float* f_u   = (const float*)d_in[2];
  const float* f_v   = (const float*)d_in[3];
  const float* jx    = (const float*)d_in[4];
  const float* jy    = (const float*)d_in[5];
  const int*   t     = (const int*)d_in[6];
  float* out = (float*)d_out;
  char* ws = (char*)d_ws;

  const size_t BHW = 1ull << 22;  // 16*512*512 elements
  float* coef  = (float*)ws;          // 64 floats
  float* norms = coef + 64;           // 32 floats
  float* fA    = (float*)(ws + 1024);       // 2*BHW floats (forcing ping)
  float* fB    = fA + 2 * BHW;              // 2*BHW floats (forcing pong)
  float* ustar = fB + 2 * BHW;              // BHW
  float* vstar = ustar + BHW;               // BHW
  float2* specA = (float2*)(vstar + BHW);   // BHW float2
  float2* specB = (float2*)ustar;           // aliases u*/v* (used after k_fluid_out)
  float* pcorr  = fB;                       // aliases fB (free after 3rd smooth)
  float* jpx    = fA;                       // aliases fA (free after k_star)
  float* jpy    = fA + BHW;

  k_coef<<<1, 64, 0, stream>>>(t, coef, norms);

  // forcing: 3 Jacobi smoothing steps, ping-pong
  k_smooth<<<32768, 256, 0, stream>>>(f_u, f_v, fA);
  k_smooth<<<32768, 256, 0, stream>>>(fA, fA + BHW, fB);
  k_smooth<<<32768, 256, 0, stream>>>(fB, fB + BHW, fA);
  k_sumsq<<<2048, 256, 0, stream>>>(fA, norms);

  // fluid star step
  k_star<<<16384, 256, 0, stream>>>(x0, noise, fA, coef, norms, ustar, vstar);

  // Poisson solve for pressure correction
  k_rowfft_div<<<2048, 256, 0, stream>>>(ustar, vstar, specA);
  k_poisson_mid<<<1024, 256, 0, stream>>>(specA);
  k_rowifft_real<<<2048, 256, 0, stream>>>(specA, pcorr);
  k_fluid_out<<<16384, 256, 0, stream>>>(x0, noise, coef, ustar, vstar, pcorr, out);

  // divergence-free projection of currents
  k_rowfft_j<<<4096, 256, 0, stream>>>(jx, jy, coef, specA, specB);
  k_project_mid<<<2048, 256, 0, stream>>>(specA, specB);
  k_rowifft_real2<<<4096, 256, 0, stream>>>(specA, specB, jpx);

  // EM updates
  k_em_bz<<<16384, 256, 0, stream>>>(x0, noise, coef, out);
  k_em_exy<<<16384, 256, 0, stream>>>(x0, noise, coef, jpx, jpy, out);
}

// Round 4
// 677.480 us; speedup vs baseline: 1.9689x; 1.9689x over previous
//
#include <hip/hip_runtime.h>
#include <math.h>

// Problem geometry: B=16, C=6, H=W=512. HW = 2^18 elements per (b, field) slab.
#define HWE 262144
#define PI2SQ4 39.478417604357434f   // 4*pi^2

__device__ __forceinline__ void wave_fence() {
  asm volatile("" ::: "memory");
  __builtin_amdgcn_wave_barrier();
}

// One wave (64 lanes) performs a 512-point complex FFT in LDS, in place,
// natural order in -> natural order out. Radix-2 DIT with bit-reversal.
// No __syncthreads: single-wave lockstep + in-order per-wave LDS.
__device__ void wave_fft512(float2* s, int lane, bool inverse) {
  wave_fence();
#pragma unroll
  for (int k = 0; k < 8; ++k) {
    int i = lane + (k << 6);
    int r = (int)(__brev((unsigned)i) >> 23);
    if (i < r) { float2 a = s[i]; float2 b = s[r]; s[i] = b; s[r] = a; }
  }
  wave_fence();
  for (int st = 0; st < 9; ++st) {
    int half = 1 << st;
#pragma unroll
    for (int k = 0; k < 4; ++k) {
      int bf = lane + (k << 6);
      int j = bf & (half - 1);
      int i0 = ((bf >> st) << (st + 1)) + j;
      int i1 = i0 + half;
      float ang = (inverse ? 6.283185307179586f : -6.283185307179586f) *
                  (float)j / (float)(half << 1);
      float sw, cw;
      __sincosf(ang, &sw, &cw);
      float2 a = s[i0], b = s[i1];
      float tr = b.x * cw - b.y * sw;
      float ti = b.x * sw + b.y * cw;
      s[i0] = make_float2(a.x + tr, a.y + ti);
      s[i1] = make_float2(a.x - tr, a.y - ti);
    }
    wave_fence();
  }
}

// --- schedule scalars (parallel): coef[b] = {sqrt(ac[t]), sqrt(1-ac[t]), sqrt(beta[t])}
// thread i computes log1p(-beta[i]); inclusive LDS scan gives log(abar[t]).
__global__ __launch_bounds__(1024) void k_coef(const int* __restrict__ t,
                                               float* __restrict__ coef,
                                               float* __restrict__ norms) {
  __shared__ double l[1024];
  int i = threadIdx.x;
  if (i < 32) norms[i] = 0.f;
  const double s = 0.008;
  const double HPI = 1.5707963267948966;
  double val = 0.0;
  if (i < 1000) {
    double c0 = cos(((double)i / 1000.0 + s) / (1.0 + s) * HPI);
    double c1 = cos(((double)(i + 1) / 1000.0 + s) / (1.0 + s) * HPI);
    double beta = 1.0 - (c1 * c1) / (c0 * c0);
    beta = fmin(fmax(beta, 0.0), 0.999);
    val = log1p(-beta);
  }
  l[i] = val;
  __syncthreads();
  for (int off = 1; off < 1024; off <<= 1) {
    double add = (i >= off) ? l[i - off] : 0.0;
    __syncthreads();
    l[i] += add;
    __syncthreads();
  }
  if (i < 16) {
    int tt = t[i];
    double ac = exp(l[tt]);
    double c0 = cos(((double)tt / 1000.0 + s) / (1.0 + s) * HPI);
    double c1 = cos(((double)(tt + 1) / 1000.0 + s) / (1.0 + s) * HPI);
    double beta = 1.0 - (c1 * c1) / (c0 * c0);
    beta = fmin(fmax(beta, 0.0), 0.999);
    coef[i * 4 + 0] = (float)sqrt(ac);
    coef[i * 4 + 1] = (float)sqrt(1.0 - ac);
    coef[i * 4 + 2] = (float)sqrt(beta);
  }
}

// --- fused: 3 Jacobi smoothing steps + sum-of-squares, tiled in LDS.
// One block = one 64x64 output tile of one slab (slab = f*16+b, 32 slabs,
// 8x8 tiles each -> 2048 blocks). Loads 70x70 with periodic halo of 3.
__global__ __launch_bounds__(256) void k_smooth3(const float* __restrict__ fu,
                                                 const float* __restrict__ fv,
                                                 float* __restrict__ dst,
                                                 float* __restrict__ norms) {
  __shared__ float sA[70 * 71];
  __shared__ float sB[70 * 71];
  __shared__ float part[4];
  int slab = blockIdx.x >> 6;
  int tile = blockIdx.x & 63;
  int tx0 = (tile & 7) << 6, ty0 = (tile >> 3) << 6;
  int b = slab & 15;
  const float* src = ((slab >> 4) ? fv : fu) + ((size_t)b << 18);
  int tid = threadIdx.x;

  for (int idx = tid; idx < 70 * 70; idx += 256) {
    int cy = idx / 70, cx = idx - cy * 70;
    int gx = (tx0 + cx - 3) & 511, gy = (ty0 + cy - 3) & 511;
    sA[cy * 71 + cx] = src[(gy << 9) + gx];
  }
  __syncthreads();
  // smooth 1: valid [1..68]^2
  for (int idx = tid; idx < 68 * 68; idx += 256) {
    int cy = idx / 68 + 1, cx = idx % 68 + 1;
    int o = cy * 71 + cx;
    float c = sA[o];
    sB[o] = c + 0.1f * (sA[o - 1] + sA[o + 1] + sA[o - 71] + sA[o + 71] - 4.f * c);
  }
  __syncthreads();
  // smooth 2: valid [2..67]^2
  for (int idx = tid; idx < 66 * 66; idx += 256) {
    int cy = idx / 66 + 2, cx = idx % 66 + 2;
    int o = cy * 71 + cx;
    float c = sB[o];
    sA[o] = c + 0.1f * (sB[o - 1] + sB[o + 1] + sB[o - 71] + sB[o + 71] - 4.f * c);
  }
  __syncthreads();
  // smooth 3 + write + sumsq: valid [3..66]^2 = 64x64
  float acc = 0.f;
  float* d = dst + ((size_t)slab << 18);
  for (int idx = tid; idx < 64 * 64; idx += 256) {
    int cy = (idx >> 6) + 3, cx = (idx & 63) + 3;
    int o = cy * 71 + cx;
    float c = sA[o];
    float v = c + 0.1f * (sA[o - 1] + sA[o + 1] + sA[o - 71] + sA[o + 71] - 4.f * c);
    d[((ty0 + cy - 3) << 9) + (tx0 + cx - 3)] = v;
    acc += v * v;
  }
  for (int off = 32; off; off >>= 1) acc += __shfl_down(acc, off, 64);
  if ((tid & 63) == 0) part[tid >> 6] = acc;
  __syncthreads();
  if (tid == 0) atomicAdd(&norms[slab], part[0] + part[1] + part[2] + part[3]);
}

#define XTL(cb, i) (sa * x0[(cb) + (i)] + so * ns[(cb) + (i)])

// --- u*, v* (advection/diffusion/pressure-grad + normalized forcing)
__global__ __launch_bounds__(256) void k_star(const float* __restrict__ x0,
    const float* __restrict__ ns, const float* __restrict__ fA,
    const float* __restrict__ coef, const float* __restrict__ norms,
    float* __restrict__ us, float* __restrict__ vs) {
  int gid = blockIdx.x * 256 + threadIdx.x;
  int x = gid & 511, y = (gid >> 9) & 511, b = gid >> 18;
  float sa = coef[b * 4], so = coef[b * 4 + 1], sb = coef[b * 4 + 2];
  int xm = (x + 511) & 511, xp = (x + 1) & 511;
  int ym = (y + 511) & 511, yp = (y + 1) & 511;
  int iC = (y << 9) + x, iXm = (y << 9) + xm, iXp = (y << 9) + xp;
  int iYm = (ym << 9) + x, iYp = (yp << 9) + x;
  int c0 = (b * 6) << 18, c1 = (b * 6 + 1) << 18, c2 = (b * 6 + 2) << 18;
  float u_c = XTL(c0, iC), u_xm = XTL(c0, iXm), u_xp = XTL(c0, iXp);
  float u_ym = XTL(c0, iYm), u_yp = XTL(c0, iYp);
  float v_c = XTL(c1, iC), v_xm = XTL(c1, iXm), v_xp = XTL(c1, iXp);
  float v_ym = XTL(c1, iYm), v_yp = XTL(c1, iYp);
  float p_xm = XTL(c2, iXm), p_xp = XTL(c2, iXp);
  float p_ym = XTL(c2, iYm), p_yp = XTL(c2, iYp);
  float adv_u = u_c * 0.5f * (u_xp - u_xm) + v_c * 0.5f * (u_yp - u_ym);
  float adv_v = u_c * 0.5f * (v_xp - v_xm) + v_c * 0.5f * (v_yp - v_ym);
  float dif_u = 0.001f * (u_xm + u_xp + u_ym + u_yp - 4.f * u_c);
  float dif_v = 0.001f * (v_xm + v_xp + v_ym + v_yp - 4.f * v_c);
  float dpx = 0.5f * (p_xp - p_xm), dpy = 0.5f * (p_yp - p_ym);
  float rnu = 1.f / fmaxf(sqrtf(norms[b]), 1e-12f);
  float rnv = 1.f / fmaxf(sqrtf(norms[16 + b]), 1e-12f);
  int bb = b << 18;
  float fu = fA[bb + iC] * rnu;
  float fv = fA[((16 + b) << 18) + iC] * rnv;
  us[bb + iC] = u_c + 0.01f * (-adv_u + dif_u - dpx) + sb * fu;
  vs[bb + iC] = v_c + 0.01f * (-adv_v + dif_v - dpy) + sb * fv;
}

// --- row FFT of div(u*, v*) computed on the fly (4 rows/block, 1 per wave)
__global__ __launch_bounds__(256) void k_rowfft_div(const float* __restrict__ us,
    const float* __restrict__ vs, float2* __restrict__ spec) {
  __shared__ float2 lds[4][512];
  int wave = threadIdx.x >> 6, lane = threadIdx.x & 63;
  int row = (blockIdx.x << 2) + wave;
  int b = row >> 9, y = row & 511;
  int ym = (y + 511) & 511, yp = (y + 1) & 511;
  const float* ub = us + ((size_t)b << 18);
  const float* vb = vs + ((size_t)b << 18);
#pragma unroll
  for (int k = 0; k < 8; ++k) {
    int xx = lane + (k << 6);
    int xm = (xx + 511) & 511, xp = (xx + 1) & 511;
    float d = 0.5f * (ub[(y << 9) + xp] - ub[(y << 9) + xm]) +
              0.5f * (vb[(yp << 9) + xx] - vb[(ym << 9) + xx]);
    lds[wave][xx] = make_float2(d, 0.f);
  }
  wave_fft512(lds[wave], lane, false);
  float2* o = spec + ((size_t)row << 9);
#pragma unroll
  for (int k = 0; k < 8; ++k) { int xx = lane + (k << 6); o[xx] = lds[wave][xx]; }
}

// --- fused column FFT + Poisson multiplier + column IFFT (8 columns/block)
__global__ __launch_bounds__(256) void k_poisson_mid(float2* __restrict__ spec) {
  __shared__ float2 lds[8][513];
  int b = blockIdx.x >> 6;
  int c0 = (blockIdx.x & 63) << 3;
  float2* sp = spec + ((size_t)b << 18);
  int c = threadIdx.x & 7, yb = threadIdx.x >> 3;
#pragma unroll
  for (int it = 0; it < 16; ++it) {
    int y = yb + (it << 5);
    lds[c][y] = sp[((size_t)y << 9) + c0 + c];
  }
  __syncthreads();
  int wave = threadIdx.x >> 6, lane = threadIdx.x & 63;
  wave_fft512(&lds[wave][0], lane, false);
  wave_fft512(&lds[wave + 4][0], lane, false);
  __syncthreads();
  const float invN2 = 1.0f / 262144.0f;
#pragma unroll
  for (int it = 0; it < 16; ++it) {
    int y = yb + (it << 5);
    int cg = c0 + c;
    float fx = (cg < 256) ? (float)cg : (float)(cg - 512);
    float fy = (y < 256) ? (float)y : (float)(y - 512);
    float k2 = fmaxf(fx * fx + fy * fy, 1e-10f);
    float m = (cg == 0 && y == 0) ? 0.f : (-invN2 / (PI2SQ4 * k2));
    float2 v = lds[c][y];
    lds[c][y] = make_float2(v.x * m, v.y * m);
  }
  __syncthreads();
  wave_fft512(&lds[wave][0], lane, true);
  wave_fft512(&lds[wave + 4][0], lane, true);
  __syncthreads();
#pragma unroll
  for (int it = 0; it < 16; ++it) {
    int y = yb + (it << 5);
    sp[((size_t)y << 9) + c0 + c] = lds[c][y];
  }
}

// --- row IFFT, keep real part (Poisson p_corr)
__global__ __launch_bounds__(256) void k_rowifft_real(const float2* __restrict__ spec,
                                                      float* __restrict__ dst) {
  __shared__ float2 lds[4][512];
  int wave = threadIdx.x >> 6, lane = threadIdx.x & 63;
  int row = (blockIdx.x << 2) + wave;
  const float2* srow = spec + ((size_t)row << 9);
#pragma unroll
  for (int k = 0; k < 8; ++k) { int xx = lane + (k << 6); lds[wave][xx] = srow[xx]; }
  wave_fft512(lds[wave], lane, true);
  float* d = dst + ((size_t)row << 9);
#pragma unroll
  for (int k = 0; k < 8; ++k) { int xx = lane + (k << 6); d[xx] = lds[wave][xx].x; }
}

// --- fluid final outputs (channels 0,1,2)
__global__ __launch_bounds__(256) void k_fluid_out(const float* __restrict__ x0,
    const float* __restrict__ ns, const float* __restrict__ coef,
    const float* __restrict__ us, const float* __restrict__ vs,
    const float* __restrict__ pc, float* __restrict__ out) {
  int gid = blockIdx.x * 256 + threadIdx.x;
  int x = gid & 511, y = (gid >> 9) & 511, b = gid >> 18;
  float sa = coef[b * 4], so = coef[b * 4 + 1];
  int xm = (x + 511) & 511, xp = (x + 1) & 511;
  int ym = (y + 511) & 511, yp = (y + 1) & 511;
  int iC = (y << 9) + x;
  int bb = b << 18;
  float pxm = pc[bb + (y << 9) + xm], pxp = pc[bb + (y << 9) + xp];
  float pym = pc[bb + (ym << 9) + x], pyp = pc[bb + (yp << 9) + x];
  float pcc = pc[bb + iC];
  int c2 = (b * 6 + 2) << 18;
  float p0 = XTL(c2, iC);
  out[((b * 6 + 0) << 18) + iC] = us[bb + iC] - 0.5f * (pxp - pxm);
  out[((b * 6 + 1) << 18) + iC] = vs[bb + iC] - 0.5f * (pyp - pym);
  out[c2 + iC] = p0 + pcc;
}

// --- row FFT of scaled currents Jx, Jy (field from blockIdx)
__global__ __launch_bounds__(256) void k_rowfft_j(const float* __restrict__ jx,
    const float* __restrict__ jy, const float* __restrict__ coef,
    float2* __restrict__ specA, float2* __restrict__ specB) {
  __shared__ float2 lds[4][512];
  int wave = threadIdx.x >> 6, lane = threadIdx.x & 63;
  int fld = blockIdx.x >> 11;
  int row = ((blockIdx.x & 2047) << 2) + wave;
  int b = row >> 9, y = row & 511;
  const float* src = fld ? jy : jx;
  float sb = coef[b * 4 + 2];
  const float* sr = src + ((size_t)b << 18) + ((size_t)y << 9);
#pragma unroll
  for (int k = 0; k < 8; ++k) {
    int xx = lane + (k << 6);
    lds[wave][xx] = make_float2(sr[xx] * sb, 0.f);
  }
  wave_fft512(lds[wave], lane, false);
  float2* o = (fld ? specB : specA) + ((size_t)row << 9);
#pragma unroll
  for (int k = 0; k < 8; ++k) { int xx = lane + (k << 6); o[xx] = lds[wave][xx]; }
}

// --- fused column FFT + Helmholtz projection + column IFFT (4 cols, 2 fields)
__global__ __launch_bounds__(256) void k_project_mid(float2* __restrict__ sx,
                                                     float2* __restrict__ sy) {
  __shared__ float2 lds[2][4][513];
  int b = blockIdx.x >> 7;
  int c0 = (blockIdx.x & 127) << 2;
  float2* spx = sx + ((size_t)b << 18);
  float2* spy = sy + ((size_t)b << 18);
  {
    int c = threadIdx.x & 3, f = (threadIdx.x >> 2) & 1, yb = threadIdx.x >> 3;
    float2* sp = f ? spy : spx;
#pragma unroll
    for (int it = 0; it < 16; ++it) {
      int y = yb + (it << 5);
      lds[f][c][y] = sp[((size_t)y << 9) + c0 + c];
    }
  }
  __syncthreads();
  int wave = threadIdx.x >> 6, lane = threadIdx.x & 63;
  wave_fft512(&lds[0][wave][0], lane, false);
  wave_fft512(&lds[1][wave][0], lane, false);
  __syncthreads();
  const float invN2 = 1.0f / 262144.0f;
  {
    int c = threadIdx.x & 3, yb = threadIdx.x >> 2;
    int cg = c0 + c;
    float fx = (cg < 256) ? (float)cg : (float)(cg - 512);
#pragma unroll
    for (int it = 0; it < 8; ++it) {
      int y = yb + (it << 6);
      float fy = (y < 256) ? (float)y : (float)(y - 512);
      float k2 = fmaxf(fx * fx + fy * fy, 1e-10f);
      float inv = 1.0f / k2;
      float2 Jx = lds[0][c][y], Jy = lds[1][c][y];
      float Dre = fx * Jx.x + fy * Jy.x;
      float Dim = fx * Jx.y + fy * Jy.y;
      lds[0][c][y] = make_float2((Jx.x - fx * Dre * inv) * invN2,
                                 (Jx.y - fx * Dim * inv) * invN2);
      lds[1][c][y] = make_float2((Jy.x - fy * Dre * inv) * invN2,
                                 (Jy.y - fy * Dim * inv) * invN2);
    }
  }
  __syncthreads();
  wave_fft512(&lds[0][wave][0], lane, true);
  wave_fft512(&lds[1][wave][0], lane, true);
  __syncthreads();
  {
    int c = threadIdx.x & 3, f = (threadIdx.x >> 2) & 1, yb = threadIdx.x >> 3;
    float2* sp = f ? spy : spx;
#pragma unroll
    for (int it = 0; it < 16; ++it) {
      int y = yb + (it << 5);
      sp[((size_t)y << 9) + c0 + c] = lds[f][c][y];
    }
  }
}

// --- row IFFT of both projected currents, keep real part
__global__ __launch_bounds__(256) void k_rowifft_real2(const float2* __restrict__ sA,
    const float2* __restrict__ sB, float* __restrict__ dst) {
  __shared__ float2 lds[4][512];
  int wave = threadIdx.x >> 6, lane = threadIdx.x & 63;
  int fld = blockIdx.x >> 11;
  int row = ((blockIdx.x & 2047) << 2) + wave;
  const float2* srow = (fld ? sB : sA) + ((size_t)row << 9);
#pragma unroll
  for (int k = 0; k < 8; ++k) { int xx = lane + (k << 6); lds[wave][xx] = srow[xx]; }
  wave_fft512(lds[wave], lane, true);
  float* d = dst + ((size_t)fld << 22) + ((size_t)row << 9);
#pragma unroll
  for (int k = 0; k < 8; ++k) { int xx = lane + (k << 6); d[xx] = lds[wave][xx].x; }
}

// --- Bz_new (channel 5)
__global__ __launch_bounds__(256) void k_em_bz(const float* __restrict__ x0,
    const float* __restrict__ ns, const float* __restrict__ coef,
    float* __restrict__ out) {
  int gid = blockIdx.x * 256 + threadIdx.x;
  int x = gid & 511, y = (gid >> 9) & 511, b = gid >> 18;
  float sa = coef[b * 4], so = coef[b * 4 + 1];
  int xm = (x + 511) & 511, xp = (x + 1) & 511;
  int ym = (y + 511) & 511, yp = (y + 1) & 511;
  int iC = (y << 9) + x;
  int c3 = (b * 6 + 3) << 18, c4 = (b * 6 + 4) << 18, c5 = (b * 6 + 5) << 18;
  float ex_ym = XTL(c3, (ym << 9) + x), ex_yp = XTL(c3, (yp << 9) + x);
  float ey_xm = XTL(c4, (y << 9) + xm), ey_xp = XTL(c4, (y << 9) + xp);
  float bz = XTL(c5, iC);
  float curl = 0.5f * (ey_xp - ey_xm) - 0.5f * (ex_yp - ex_ym);
  out[c5 + iC] = bz - 0.01f * curl;   // DT/MU = 0.01
}

// --- Ex_new, Ey_new (channels 3,4) reading Bz_new from out
__global__ __launch_bounds__(256) void k_em_exy(const float* __restrict__ x0,
    const float* __restrict__ ns, const float* __restrict__ coef,
    const float* __restrict__ jpx, const float* __restrict__ jpy,
    float* __restrict__ out) {
  int gid = blockIdx.x * 256 + threadIdx.x;
  int x = gid & 511, y = (gid >> 9) & 511, b = gid >> 18;
  float sa = coef[b * 4], so = coef[b * 4 + 1];
  int xm = (x + 511) & 511, xp = (x + 1) & 511;
  int ym = (y + 511) & 511, yp = (y + 1) & 511;
  int iC = (y << 9) + x;
  int c3 = (b * 6 + 3) << 18, c4 = (b * 6 + 4) << 18, c5 = (b * 6 + 5) << 18;
  const float* bzn = out + c5;
  float ddyB = 0.5f * (bzn[(yp << 9) + x] - bzn[(ym << 9) + x]);
  float ddxB = 0.5f * (bzn[(y << 9) + xp] - bzn[(y << 9) + xm]);
  float ex = XTL(c3, iC);
  float ey = XTL(c4, iC);
  int bb = b << 18;
  out[c3 + iC] = ex + 0.01f * ddyB - 0.01f * jpx[bb + iC];  // DT/EPS = 0.01
  out[c4 + iC] = ey - 0.01f * ddxB - 0.01f * jpy[bb + iC];
}

extern "C" void kernel_launch(void* const* d_in, const int* in_sizes, int n_in,
                              void* d_out, int out_size, void* d_ws, size_t ws_size,
                              hipStream_t stream) {
  const float* x0    = (const float*)d_in[0];
  const float* noise = (const float*)d_in[1];
  const float* f_u   = (const float*)d_in[2];
  const float* f_v   = (const float*)d_in[3];
  const float* jx    = (const float*)d_in[4];
  const float* jy    = (const float*)d_in[5];
  const int*   t     = (const int*)d_in[6];
  float* out = (float*)d_out;
  char* ws = (char*)d_ws;

  const size_t BHW = 1ull << 22;  // 16*512*512 elements
  float* coef  = (float*)ws;          // 64 floats
  float* norms = coef + 64;           // 32 floats
  float* fA    = (float*)(ws + 1024);       // 2*BHW floats (forcing, smoothed)
  float* fB    = fA + 2 * BHW;              // 2*BHW floats (now only pcorr alias)
  float* ustar = fB + 2 * BHW;              // BHW
  float* vstar = ustar + BHW;               // BHW
  float2* specA = (float2*)(vstar + BHW);   // BHW float2
  float2* specB = (float2*)ustar;           // aliases u*/v* (used after k_fluid_out)
  float* pcorr  = fB;                       // free region
  float* jpx    = fA;                       // aliases fA (free after k_star)
  float* jpy    = fA + BHW;

  k_coef<<<1, 1024, 0, stream>>>(t, coef, norms);

  // forcing: 3 fused Jacobi smoothing steps + sumsq
  k_smooth3<<<2048, 256, 0, stream>>>(f_u, f_v, fA, norms);

  // fluid star step
  k_star<<<16384, 256, 0, stream>>>(x0, noise, fA, coef, norms, ustar, vstar);

  // Poisson solve for pressure correction
  k_rowfft_div<<<2048, 256, 0, stream>>>(ustar, vstar, specA);
  k_poisson_mid<<<1024, 256, 0, stream>>>(specA);
  k_rowifft_real<<<2048, 256, 0, stream>>>(specA, pcorr);
  k_fluid_out<<<16384, 256, 0, stream>>>(x0, noise, coef, ustar, vstar, pcorr, out);

  // divergence-free projection of currents
  k_rowfft_j<<<4096, 256, 0, stream>>>(jx, jy, coef, specA, specB);
  k_project_mid<<<2048, 256, 0, stream>>>(specA, specB);
  k_rowifft_real2<<<4096, 256, 0, stream>>>(specA, specB, jpx);

  // EM updates
  k_em_bz<<<16384, 256, 0, stream>>>(x0, noise, coef, out);
  k_em_exy<<<16384, 256, 0, stream>>>(x0, noise, coef, jpx, jpy, out);
}

// Round 5
// 534.907 us; speedup vs baseline: 2.4937x; 1.2665x over previous
//
#include <hip/hip_runtime.h>
#include <math.h>

// Problem geometry: B=16, C=6, H=W=512. HW = 2^18 elements per (b, field) slab.
#define PI2SQ4 39.478417604357434f   // 4*pi^2
#define FSTRIDE 545                  // float2 stride per FFT buffer (545*2 banks = 2 mod 32)
#define IDX(i) ((i) + ((i) >> 4))    // intra-buffer pad: +1 float2 per 16

__device__ __forceinline__ void wave_fence() {
  asm volatile("" ::: "memory");
  __builtin_amdgcn_wave_barrier();
}

// One wave performs a 512-point complex FFT in place on a padded LDS buffer
// (logical index i lives at s[IDX(i)]). Twiddles from LDS table tw[256],
// tw[j] = exp(-2*pi*i*j/512). isign=+1 forward, -1 inverse (no 1/N scaling).
__device__ void wave_fft512(float2* s, const float2* tw, int lane, float isign) {
  wave_fence();
#pragma unroll
  for (int k = 0; k < 8; ++k) {
    int i = lane + (k << 6);
    int r = (int)(__brev((unsigned)i) >> 23);
    if (i < r) { float2 a = s[IDX(i)]; float2 b = s[IDX(r)]; s[IDX(i)] = b; s[IDX(r)] = a; }
  }
  wave_fence();
  for (int st = 0; st < 9; ++st) {
    int half = 1 << st;
#pragma unroll
    for (int k = 0; k < 4; ++k) {
      int bf = lane + (k << 6);
      int j = bf & (half - 1);
      int i0 = ((bf >> st) << (st + 1)) + j;
      int i1 = i0 + half;
      float2 w = tw[j << (8 - st)];
      float cw = w.x, sw = w.y * isign;
      float2 a = s[IDX(i0)], b = s[IDX(i1)];
      float tr = b.x * cw - b.y * sw;
      float ti = b.x * sw + b.y * cw;
      s[IDX(i0)] = make_float2(a.x + tr, a.y + ti);
      s[IDX(i1)] = make_float2(a.x - tr, a.y - ti);
    }
    wave_fence();
  }
}

__device__ __forceinline__ void tw_init(float2* tw, int tid) {
  if (tid < 256) {
    float sw, cw;
    __sincosf((float)tid * -0.012271846303085128f, &sw, &cw);  // -2*pi/512
    tw[tid] = make_float2(cw, sw);
  }
}

// --- schedule scalars (parallel): coef[b] = {sqrt(ac[t]), sqrt(1-ac[t]), sqrt(beta[t])}
__global__ __launch_bounds__(1024) void k_coef(const int* __restrict__ t,
                                               float* __restrict__ coef,
                                               float* __restrict__ norms) {
  __shared__ double l[1024];
  int i = threadIdx.x;
  if (i < 32) norms[i] = 0.f;
  const double s = 0.008;
  const double HPI = 1.5707963267948966;
  double val = 0.0;
  if (i < 1000) {
    double c0 = cos(((double)i / 1000.0 + s) / (1.0 + s) * HPI);
    double c1 = cos(((double)(i + 1) / 1000.0 + s) / (1.0 + s) * HPI);
    double beta = 1.0 - (c1 * c1) / (c0 * c0);
    beta = fmin(fmax(beta, 0.0), 0.999);
    val = log1p(-beta);
  }
  l[i] = val;
  __syncthreads();
  for (int off = 1; off < 1024; off <<= 1) {
    double add = (i >= off) ? l[i - off] : 0.0;
    __syncthreads();
    l[i] += add;
    __syncthreads();
  }
  if (i < 16) {
    int tt = t[i];
    double ac = exp(l[tt]);
    double c0 = cos(((double)tt / 1000.0 + s) / (1.0 + s) * HPI);
    double c1 = cos(((double)(tt + 1) / 1000.0 + s) / (1.0 + s) * HPI);
    double beta = 1.0 - (c1 * c1) / (c0 * c0);
    beta = fmin(fmax(beta, 0.0), 0.999);
    coef[i * 4 + 0] = (float)sqrt(ac);
    coef[i * 4 + 1] = (float)sqrt(1.0 - ac);
    coef[i * 4 + 2] = (float)sqrt(beta);
  }
}

// --- fused: 3 Jacobi smoothing steps + sum-of-squares, tiled in LDS.
__global__ __launch_bounds__(256) void k_smooth3(const float* __restrict__ fu,
                                                 const float* __restrict__ fv,
                                                 float* __restrict__ dst,
                                                 float* __restrict__ norms) {
  __shared__ float sA[70 * 71];
  __shared__ float sB[70 * 71];
  __shared__ float part[4];
  int slab = blockIdx.x >> 6;
  int tile = blockIdx.x & 63;
  int tx0 = (tile & 7) << 6, ty0 = (tile >> 3) << 6;
  int b = slab & 15;
  const float* src = ((slab >> 4) ? fv : fu) + ((size_t)b << 18);
  int tid = threadIdx.x;

  for (int idx = tid; idx < 70 * 70; idx += 256) {
    int cy = idx / 70, cx = idx - cy * 70;
    int gx = (tx0 + cx - 3) & 511, gy = (ty0 + cy - 3) & 511;
    sA[cy * 71 + cx] = src[(gy << 9) + gx];
  }
  __syncthreads();
  for (int idx = tid; idx < 68 * 68; idx += 256) {
    int cy = idx / 68 + 1, cx = idx % 68 + 1;
    int o = cy * 71 + cx;
    float c = sA[o];
    sB[o] = c + 0.1f * (sA[o - 1] + sA[o + 1] + sA[o - 71] + sA[o + 71] - 4.f * c);
  }
  __syncthreads();
  for (int idx = tid; idx < 66 * 66; idx += 256) {
    int cy = idx / 66 + 2, cx = idx % 66 + 2;
    int o = cy * 71 + cx;
    float c = sB[o];
    sA[o] = c + 0.1f * (sB[o - 1] + sB[o + 1] + sB[o - 71] + sB[o + 71] - 4.f * c);
  }
  __syncthreads();
  float acc = 0.f;
  float* d = dst + ((size_t)slab << 18);
  for (int idx = tid; idx < 64 * 64; idx += 256) {
    int cy = (idx >> 6) + 3, cx = (idx & 63) + 3;
    int o = cy * 71 + cx;
    float c = sA[o];
    float v = c + 0.1f * (sA[o - 1] + sA[o + 1] + sA[o - 71] + sA[o + 71] - 4.f * c);
    d[((ty0 + cy - 3) << 9) + (tx0 + cx - 3)] = v;
    acc += v * v;
  }
  for (int off = 32; off; off >>= 1) acc += __shfl_down(acc, off, 64);
  if ((tid & 63) == 0) part[tid >> 6] = acc;
  __syncthreads();
  if (tid == 0) atomicAdd(&norms[slab], part[0] + part[1] + part[2] + part[3]);
}

#define XTL(cb, i) (sa * x0[(cb) + (i)] + so * ns[(cb) + (i)])

// --- u*, v* (advection/diffusion/pressure-grad + normalized forcing)
__global__ __launch_bounds__(256) void k_star(const float* __restrict__ x0,
    const float* __restrict__ ns, const float* __restrict__ fA,
    const float* __restrict__ coef, const float* __restrict__ norms,
    float* __restrict__ us, float* __restrict__ vs) {
  int gid = blockIdx.x * 256 + threadIdx.x;
  int x = gid & 511, y = (gid >> 9) & 511, b = gid >> 18;
  float sa = coef[b * 4], so = coef[b * 4 + 1], sb = coef[b * 4 + 2];
  int xm = (x + 511) & 511, xp = (x + 1) & 511;
  int ym = (y + 511) & 511, yp = (y + 1) & 511;
  int iC = (y << 9) + x, iXm = (y << 9) + xm, iXp = (y << 9) + xp;
  int iYm = (ym << 9) + x, iYp = (yp << 9) + x;
  int c0 = (b * 6) << 18, c1 = (b * 6 + 1) << 18, c2 = (b * 6 + 2) << 18;
  float u_c = XTL(c0, iC), u_xm = XTL(c0, iXm), u_xp = XTL(c0, iXp);
  float u_ym = XTL(c0, iYm), u_yp = XTL(c0, iYp);
  float v_c = XTL(c1, iC), v_xm = XTL(c1, iXm), v_xp = XTL(c1, iXp);
  float v_ym = XTL(c1, iYm), v_yp = XTL(c1, iYp);
  float p_xm = XTL(c2, iXm), p_xp = XTL(c2, iXp);
  float p_ym = XTL(c2, iYm), p_yp = XTL(c2, iYp);
  float adv_u = u_c * 0.5f * (u_xp - u_xm) + v_c * 0.5f * (u_yp - u_ym);
  float adv_v = u_c * 0.5f * (v_xp - v_xm) + v_c * 0.5f * (v_yp - v_ym);
  float dif_u = 0.001f * (u_xm + u_xp + u_ym + u_yp - 4.f * u_c);
  float dif_v = 0.001f * (v_xm + v_xp + v_ym + v_yp - 4.f * v_c);
  float dpx = 0.5f * (p_xp - p_xm), dpy = 0.5f * (p_yp - p_ym);
  float rnu = 1.f / fmaxf(sqrtf(norms[b]), 1e-12f);
  float rnv = 1.f / fmaxf(sqrtf(norms[16 + b]), 1e-12f);
  int bb = b << 18;
  float fu = fA[bb + iC] * rnu;
  float fv = fA[((16 + b) << 18) + iC] * rnv;
  us[bb + iC] = u_c + 0.01f * (-adv_u + dif_u - dpx) + sb * fu;
  vs[bb + iC] = v_c + 0.01f * (-adv_v + dif_v - dpy) + sb * fv;
}

// --- row FFT of packed divergence: q = div_b + i*div_{b+8}, batch pairs pb=0..7
__global__ __launch_bounds__(256) void k_rowfft_div(const float* __restrict__ us,
    const float* __restrict__ vs, float2* __restrict__ spec) {
  __shared__ float2 buf[4 * FSTRIDE];
  __shared__ float2 tw[256];
  int tid = threadIdx.x;
  tw_init(tw, tid);
  int wave = tid >> 6, lane = tid & 63;
  int rid = (blockIdx.x << 2) + wave;   // 0..4095
  int pb = rid >> 9, y = rid & 511;
  int ym = (y + 511) & 511, yp = (y + 1) & 511;
  const float* ul = us + ((size_t)pb << 18);
  const float* vl = vs + ((size_t)pb << 18);
  const float* uh = us + ((size_t)(pb + 8) << 18);
  const float* vh = vs + ((size_t)(pb + 8) << 18);
  float2* s = buf + wave * FSTRIDE;
  __syncthreads();
#pragma unroll
  for (int k = 0; k < 8; ++k) {
    int xx = lane + (k << 6);
    int xm = (xx + 511) & 511, xp = (xx + 1) & 511;
    float dlo = 0.5f * (ul[(y << 9) + xp] - ul[(y << 9) + xm]) +
                0.5f * (vl[(yp << 9) + xx] - vl[(ym << 9) + xx]);
    float dhi = 0.5f * (uh[(y << 9) + xp] - uh[(y << 9) + xm]) +
                0.5f * (vh[(yp << 9) + xx] - vh[(ym << 9) + xx]);
    s[IDX(xx)] = make_float2(dlo, dhi);
  }
  wave_fft512(s, tw, lane, 1.f);
  float2* o = spec + ((size_t)rid << 9);
#pragma unroll
  for (int k = 0; k < 8; ++k) { int xx = lane + (k << 6); o[xx] = s[IDX(xx)]; }
}

// --- fused column FFT + Poisson multiplier + column IFFT (8 cols/block, 8 batch-pairs)
__global__ __launch_bounds__(256) void k_poisson_mid(float2* __restrict__ spec) {
  __shared__ float2 buf[8 * FSTRIDE];
  __shared__ float2 tw[256];
  int tid = threadIdx.x;
  tw_init(tw, tid);
  int pb = blockIdx.x >> 6;
  int c0 = (blockIdx.x & 63) << 3;
  float2* sp = spec + ((size_t)pb << 18);
  int c = tid & 7, yb = tid >> 3;
  __syncthreads();
#pragma unroll
  for (int it = 0; it < 16; ++it) {
    int y = yb + (it << 5);
    buf[c * FSTRIDE + IDX(y)] = sp[((size_t)y << 9) + c0 + c];
  }
  __syncthreads();
  int wave = tid >> 6, lane = tid & 63;
  wave_fft512(buf + wave * FSTRIDE, tw, lane, 1.f);
  wave_fft512(buf + (wave + 4) * FSTRIDE, tw, lane, 1.f);
  __syncthreads();
  const float invN2 = 1.0f / 262144.0f;
#pragma unroll
  for (int it = 0; it < 16; ++it) {
    int y = yb + (it << 5);
    int cg = c0 + c;
    float fx = (cg < 256) ? (float)cg : (float)(cg - 512);
    float fy = (y < 256) ? (float)y : (float)(y - 512);
    float k2 = fmaxf(fx * fx + fy * fy, 1e-10f);
    float m = (cg == 0 && y == 0) ? 0.f : (-invN2 / (PI2SQ4 * k2));
    float2 v = buf[c * FSTRIDE + IDX(y)];
    buf[c * FSTRIDE + IDX(y)] = make_float2(v.x * m, v.y * m);
  }
  __syncthreads();
  wave_fft512(buf + wave * FSTRIDE, tw, lane, -1.f);
  wave_fft512(buf + (wave + 4) * FSTRIDE, tw, lane, -1.f);
  __syncthreads();
#pragma unroll
  for (int it = 0; it < 16; ++it) {
    int y = yb + (it << 5);
    sp[((size_t)y << 9) + c0 + c] = buf[c * FSTRIDE + IDX(y)];
  }
}

// --- row IFFT of packed Poisson solution; re->pcorr[pb], im->pcorr[pb+8]
__global__ __launch_bounds__(256) void k_rowifft_real(const float2* __restrict__ spec,
                                                      float* __restrict__ pcorr) {
  __shared__ float2 buf[4 * FSTRIDE];
  __shared__ float2 tw[256];
  int tid = threadIdx.x;
  tw_init(tw, tid);
  int wave = tid >> 6, lane = tid & 63;
  int rid = (blockIdx.x << 2) + wave;
  int pb = rid >> 9, y = rid & 511;
  const float2* srow = spec + ((size_t)rid << 9);
  float2* s = buf + wave * FSTRIDE;
  __syncthreads();
#pragma unroll
  for (int k = 0; k < 8; ++k) { int xx = lane + (k << 6); s[IDX(xx)] = srow[xx]; }
  wave_fft512(s, tw, lane, -1.f);
  float* dlo = pcorr + ((size_t)pb << 18) + ((size_t)y << 9);
  float* dhi = pcorr + ((size_t)(pb + 8) << 18) + ((size_t)y << 9);
#pragma unroll
  for (int k = 0; k < 8; ++k) {
    int xx = lane + (k << 6);
    float2 v = s[IDX(xx)];
    dlo[xx] = v.x;
    dhi[xx] = v.y;
  }
}

// --- fluid final outputs (channels 0,1,2)
__global__ __launch_bounds__(256) void k_fluid_out(const float* __restrict__ x0,
    const float* __restrict__ ns, const float* __restrict__ coef,
    const float* __restrict__ us, const float* __restrict__ vs,
    const float* __restrict__ pc, float* __restrict__ out) {
  int gid = blockIdx.x * 256 + threadIdx.x;
  int x = gid & 511, y = (gid >> 9) & 511, b = gid >> 18;
  float sa = coef[b * 4], so = coef[b * 4 + 1];
  int xm = (x + 511) & 511, xp = (x + 1) & 511;
  int ym = (y + 511) & 511, yp = (y + 1) & 511;
  int iC = (y << 9) + x;
  int bb = b << 18;
  float pxm = pc[bb + (y << 9) + xm], pxp = pc[bb + (y << 9) + xp];
  float pym = pc[bb + (ym << 9) + x], pyp = pc[bb + (yp << 9) + x];
  float pcc = pc[bb + iC];
  int c2 = (b * 6 + 2) << 18;
  float p0 = XTL(c2, iC);
  out[((b * 6 + 0) << 18) + iC] = us[bb + iC] - 0.5f * (pxp - pxm);
  out[((b * 6 + 1) << 18) + iC] = vs[bb + iC] - 0.5f * (pyp - pym);
  out[c2 + iC] = p0 + pcc;
}

// --- row FFT of packed currents q = sb*(jx + i*jy)
__global__ __launch_bounds__(256) void k_rowfft_q(const float* __restrict__ jx,
    const float* __restrict__ jy, const float* __restrict__ coef,
    float2* __restrict__ spec) {
  __shared__ float2 buf[4 * FSTRIDE];
  __shared__ float2 tw[256];
  int tid = threadIdx.x;
  tw_init(tw, tid);
  int wave = tid >> 6, lane = tid & 63;
  int row = (blockIdx.x << 2) + wave;    // 0..8191
  int b = row >> 9, y = row & 511;
  float sb = coef[b * 4 + 2];
  const float* jxr = jx + ((size_t)b << 18) + ((size_t)y << 9);
  const float* jyr = jy + ((size_t)b << 18) + ((size_t)y << 9);
  float2* s = buf + wave * FSTRIDE;
  __syncthreads();
#pragma unroll
  for (int k = 0; k < 8; ++k) {
    int xx = lane + (k << 6);
    s[IDX(xx)] = make_float2(jxr[xx] * sb, jyr[xx] * sb);
  }
  wave_fft512(s, tw, lane, 1.f);
  float2* o = spec + ((size_t)row << 9);
#pragma unroll
  for (int k = 0; k < 8; ++k) { int xx = lane + (k << 6); o[xx] = s[IDX(xx)]; }
}

// column index for slot c (0..7) of mirror-block jj (0..63)
__device__ __forceinline__ int colof(int jj, int c) {
  int col = (c < 4) ? ((jj << 2) + c) : ((512 - (jj << 2) - 3 + (c - 4)) & 511);
  if (jj == 0 && c == 7) col = 256;
  return col;
}

// Hermitian separation + projection + recombination for one mirror pair.
// Reads F(k) at (cc,yy) and F(-k) at (mcc,my); writes G(k) and G(-k).
__device__ __forceinline__ void proj_pair(float2* buf, int jj, int cc, int yy, int mcc) {
  int my = (512 - yy) & 511;
  float2 F1 = buf[cc * FSTRIDE + IDX(yy)];
  float2 F2 = buf[mcc * FSTRIDE + IDX(my)];
  float Jxr = 0.5f * (F1.x + F2.x), Jxi = 0.5f * (F1.y - F2.y);
  float Jyr = 0.5f * (F1.y + F2.y), Jyi = 0.5f * (F2.x - F1.x);
  int colc = colof(jj, cc);
  float fx = (colc < 256) ? (float)colc : (float)(colc - 512);
  float fy = (yy < 256) ? (float)yy : (float)(yy - 512);
  float k2 = fmaxf(fx * fx + fy * fy, 1e-10f);
  float inv = 1.0f / k2;
  float Dr = fx * Jxr + fy * Jyr, Di = fx * Jxi + fy * Jyi;
  const float invN2 = 1.0f / 262144.0f;
  float Jxr2 = (Jxr - fx * Dr * inv) * invN2, Jxi2 = (Jxi - fx * Di * inv) * invN2;
  float Jyr2 = (Jyr - fy * Dr * inv) * invN2, Jyi2 = (Jyi - fy * Di * inv) * invN2;
  buf[cc * FSTRIDE + IDX(yy)]  = make_float2(Jxr2 - Jyi2, Jxi2 + Jyr2);
  buf[mcc * FSTRIDE + IDX(my)] = make_float2(Jxr2 + Jyi2, Jyr2 - Jxi2);
}

// --- fused column FFT + Helmholtz projection + column IFFT on packed spectrum.
// Block = batch bb x mirror column octet jj. 1024 blocks.
__global__ __launch_bounds__(256) void k_project_mid(float2* __restrict__ spec) {
  __shared__ float2 buf[8 * FSTRIDE];
  __shared__ float2 tw[256];
  int tid = threadIdx.x;
  tw_init(tw, tid);
  int bb = blockIdx.x >> 6;
  int jj = blockIdx.x & 63;
  float2* sp = spec + ((size_t)bb << 18);
  int c = tid & 7, yb = tid >> 3;
  int mycol = colof(jj, c);
  __syncthreads();
#pragma unroll
  for (int it = 0; it < 16; ++it) {
    int y = yb + (it << 5);
    buf[c * FSTRIDE + IDX(y)] = sp[((size_t)y << 9) + mycol];
  }
  __syncthreads();
  int wave = tid >> 6, lane = tid & 63;
  wave_fft512(buf + wave * FSTRIDE, tw, lane, 1.f);
  wave_fft512(buf + (wave + 4) * FSTRIDE, tw, lane, 1.f);
  __syncthreads();
  // separation + projection + recombination (hazard-free pair ownership)
#pragma unroll
  for (int it = 0; it < 8; ++it) {
    int tIdx = (it << 8) + tid;       // 0..2047
    int cc = tIdx >> 9, y = tIdx & 511;
    if (jj == 0 && cc == 0) {
      if (y > 256) {
        proj_pair(buf, 0, 7, y - 256, 7);       // col 256 tasks, yy = 1..255
      } else {
        proj_pair(buf, 0, 0, y, 0);             // col 0 tasks, yy = 0..256
        if (y == 0 || y == 256) proj_pair(buf, 0, 7, y, 7);  // col 256 self rows
      }
    } else {
      proj_pair(buf, jj, cc, y, 7 - cc);
    }
  }
  __syncthreads();
  wave_fft512(buf + wave * FSTRIDE, tw, lane, -1.f);
  wave_fft512(buf + (wave + 4) * FSTRIDE, tw, lane, -1.f);
  __syncthreads();
#pragma unroll
  for (int it = 0; it < 16; ++it) {
    int y = yb + (it << 5);
    sp[((size_t)y << 9) + mycol] = buf[c * FSTRIDE + IDX(y)];
  }
}

// --- row IFFT of projected packed spectrum; re->jpx, im->jpy
__global__ __launch_bounds__(256) void k_rowifft_j(const float2* __restrict__ spec,
                                                   float* __restrict__ jpx,
                                                   float* __restrict__ jpy) {
  __shared__ float2 buf[4 * FSTRIDE];
  __shared__ float2 tw[256];
  int tid = threadIdx.x;
  tw_init(tw, tid);
  int wave = tid >> 6, lane = tid & 63;
  int row = (blockIdx.x << 2) + wave;
  const float2* srow = spec + ((size_t)row << 9);
  float2* s = buf + wave * FSTRIDE;
  __syncthreads();
#pragma unroll
  for (int k = 0; k < 8; ++k) { int xx = lane + (k << 6); s[IDX(xx)] = srow[xx]; }
  wave_fft512(s, tw, lane, -1.f);
  float* dx = jpx + ((size_t)row << 9);
  float* dy = jpy + ((size_t)row << 9);
#pragma unroll
  for (int k = 0; k < 8; ++k) {
    int xx = lane + (k << 6);
    float2 v = s[IDX(xx)];
    dx[xx] = v.x;
    dy[xx] = v.y;
  }
}

// --- Bz_new (channel 5)
__global__ __launch_bounds__(256) void k_em_bz(const float* __restrict__ x0,
    const float* __restrict__ ns, const float* __restrict__ coef,
    float* __restrict__ out) {
  int gid = blockIdx.x * 256 + threadIdx.x;
  int x = gid & 511, y = (gid >> 9) & 511, b = gid >> 18;
  float sa = coef[b * 4], so = coef[b * 4 + 1];
  int xm = (x + 511) & 511, xp = (x + 1) & 511;
  int ym = (y + 511) & 511, yp = (y + 1) & 511;
  int iC = (y << 9) + x;
  int c3 = (b * 6 + 3) << 18, c4 = (b * 6 + 4) << 18, c5 = (b * 6 + 5) << 18;
  float ex_ym = XTL(c3, (ym << 9) + x), ex_yp = XTL(c3, (yp << 9) + x);
  float ey_xm = XTL(c4, (y << 9) + xm), ey_xp = XTL(c4, (y << 9) + xp);
  float bz = XTL(c5, iC);
  float curl = 0.5f * (ey_xp - ey_xm) - 0.5f * (ex_yp - ex_ym);
  out[c5 + iC] = bz - 0.01f * curl;   // DT/MU = 0.01
}

// --- Ex_new, Ey_new (channels 3,4) reading Bz_new from out
__global__ __launch_bounds__(256) void k_em_exy(const float* __restrict__ x0,
    const float* __restrict__ ns, const float* __restrict__ coef,
    const float* __restrict__ jpx, const float* __restrict__ jpy,
    float* __restrict__ out) {
  int gid = blockIdx.x * 256 + threadIdx.x;
  int x = gid & 511, y = (gid >> 9) & 511, b = gid >> 18;
  float sa = coef[b * 4], so = coef[b * 4 + 1];
  int xm = (x + 511) & 511, xp = (x + 1) & 511;
  int ym = (y + 511) & 511, yp = (y + 1) & 511;
  int iC = (y << 9) + x;
  int c3 = (b * 6 + 3) << 18, c4 = (b * 6 + 4) << 18, c5 = (b * 6 + 5) << 18;
  const float* bzn = out + c5;
  float ddyB = 0.5f * (bzn[(yp << 9) + x] - bzn[(ym << 9) + x]);
  float ddxB = 0.5f * (bzn[(y << 9) + xp] - bzn[(y << 9) + xm]);
  float ex = XTL(c3, iC);
  float ey = XTL(c4, iC);
  int bb = b << 18;
  out[c3 + iC] = ex + 0.01f * ddyB - 0.01f * jpx[bb + iC];  // DT/EPS = 0.01
  out[c4 + iC] = ey - 0.01f * ddxB - 0.01f * jpy[bb + iC];
}

extern "C" void kernel_launch(void* const* d_in, const int* in_sizes, int n_in,
                              void* d_out, int out_size, void* d_ws, size_t ws_size,
                              hipStream_t stream) {
  const float* x0    = (const float*)d_in[0];
  const float* noise = (const float*)d_in[1];
  const float* f_u   = (const float*)d_in[2];
  const float* f_v   = (const float*)d_in[3];
  const float* jx    = (const float*)d_in[4];
  const float* jy    = (const float*)d_in[5];
  const int*   t     = (const int*)d_in[6];
  float* out = (float*)d_out;
  char* ws = (char*)d_ws;

  const size_t BHW = 1ull << 22;  // 16*512*512 elements
  float* coef  = (float*)ws;                 // 64 floats
  float* norms = coef + 64;                  // 32 floats
  float* fA    = (float*)(ws + 1024);        // 2*BHW (forcing; later jpx/jpy)
  float* pcorr = fA + 2 * BHW;               // BHW
  float* ustar = pcorr + BHW;                // BHW
  float* vstar = ustar + BHW;                // BHW
  float2* specP = (float2*)(vstar + BHW);    // BHW/2 complex (8 batch-pairs)
  float2* specJ = (float2*)ustar;            // BHW complex, aliases ustar+vstar
  float* jpx   = fA;                         // aliases fA (free after k_star)
  float* jpy   = fA + BHW;

  k_coef<<<1, 1024, 0, stream>>>(t, coef, norms);

  // forcing: 3 fused Jacobi smoothing steps + sumsq
  k_smooth3<<<2048, 256, 0, stream>>>(f_u, f_v, fA, norms);

  // fluid star step
  k_star<<<16384, 256, 0, stream>>>(x0, noise, fA, coef, norms, ustar, vstar);

  // Poisson solve for pressure correction (batch-pair packed)
  k_rowfft_div<<<1024, 256, 0, stream>>>(ustar, vstar, specP);
  k_poisson_mid<<<512, 256, 0, stream>>>(specP);
  k_rowifft_real<<<1024, 256, 0, stream>>>(specP, pcorr);
  k_fluid_out<<<16384, 256, 0, stream>>>(x0, noise, coef, ustar, vstar, pcorr, out);

  // divergence-free projection of currents (jx+i*jy packed)
  k_rowfft_q<<<2048, 256, 0, stream>>>(jx, jy, coef, specJ);
  k_project_mid<<<1024, 256, 0, stream>>>(specJ);
  k_rowifft_j<<<2048, 256, 0, stream>>>(specJ, jpx, jpy);

  // EM updates
  k_em_bz<<<16384, 256, 0, stream>>>(x0, noise, coef, out);
  k_em_exy<<<16384, 256, 0, stream>>>(x0, noise, coef, jpx, jpy, out);
}

// Round 7
// 526.521 us; speedup vs baseline: 2.5334x; 1.0159x over previous
//
#include <hip/hip_runtime.h>
#include <math.h>

// Problem geometry: B=16, C=6, H=W=512. HW = 2^18 elements per (b, field) slab.
#define PI2SQ4 39.478417604357434f   // 4*pi^2
#define FSTRIDE 545                  // float2 stride per FFT buffer
#define IDX(i) ((i) + ((i) >> 4))    // intra-buffer pad: +1 float2 per 16

__device__ __forceinline__ void wave_fence() {
  asm volatile("" ::: "memory");
  __builtin_amdgcn_wave_barrier();
}

__device__ __forceinline__ float4 ld4(const float* p) {
  return *reinterpret_cast<const float4*>(p);
}
__device__ __forceinline__ void st4(float* p, float4 v) {
  *reinterpret_cast<float4*>(p) = v;
}
__device__ __forceinline__ float fc(const float4& v, int j) {
  return j == 0 ? v.x : j == 1 ? v.y : j == 2 ? v.z : v.w;
}
__device__ __forceinline__ float fc8(const float4& a, const float4& b, int j) {
  return j < 4 ? fc(a, j) : fc(b, j - 4);
}
// xt = sqrt(abar)*x0 + sqrt(1-abar)*noise, 4 consecutive elements
__device__ __forceinline__ float4 xtl4(const float* x0, const float* ns, int off,
                                       float sa, float so) {
  float4 a = ld4(x0 + off), b = ld4(ns + off);
  return make_float4(sa * a.x + so * b.x, sa * a.y + so * b.y,
                     sa * a.z + so * b.z, sa * a.w + so * b.w);
}

// One wave performs a 512-point complex FFT in place on a padded LDS buffer.
// Twiddles from LDS table tw[256], tw[j]=exp(-2*pi*i*j/512). isign=+1 fwd, -1 inv.
__device__ void wave_fft512(float2* s, const float2* tw, int lane, float isign) {
  wave_fence();
#pragma unroll
  for (int k = 0; k < 8; ++k) {
    int i = lane + (k << 6);
    int r = (int)(__brev((unsigned)i) >> 23);
    if (i < r) { float2 a = s[IDX(i)]; float2 b = s[IDX(r)]; s[IDX(i)] = b; s[IDX(r)] = a; }
  }
  wave_fence();
  for (int st = 0; st < 9; ++st) {
    int half = 1 << st;
#pragma unroll
    for (int k = 0; k < 4; ++k) {
      int bf = lane + (k << 6);
      int j = bf & (half - 1);
      int i0 = ((bf >> st) << (st + 1)) + j;
      int i1 = i0 + half;
      float2 w = tw[j << (8 - st)];
      float cw = w.x, sw = w.y * isign;
      float2 a = s[IDX(i0)], b = s[IDX(i1)];
      float tr = b.x * cw - b.y * sw;
      float ti = b.x * sw + b.y * cw;
      s[IDX(i0)] = make_float2(a.x + tr, a.y + ti);
      s[IDX(i1)] = make_float2(a.x - tr, a.y - ti);
    }
    wave_fence();
  }
}

__device__ __forceinline__ void tw_init(float2* tw, int tid) {
  if (tid < 256) {
    float sw, cw;
    __sincosf((float)tid * -0.012271846303085128f, &sw, &cw);  // -2*pi/512
    tw[tid] = make_float2(cw, sw);
  }
}

// --- schedule scalars (parallel scan)
__global__ __launch_bounds__(1024) void k_coef(const int* __restrict__ t,
                                               float* __restrict__ coef,
                                               float* __restrict__ norms) {
  __shared__ double l[1024];
  int i = threadIdx.x;
  if (i < 32) norms[i] = 0.f;
  const double s = 0.008;
  const double HPI = 1.5707963267948966;
  double val = 0.0;
  if (i < 1000) {
    double c0 = cos(((double)i / 1000.0 + s) / (1.0 + s) * HPI);
    double c1 = cos(((double)(i + 1) / 1000.0 + s) / (1.0 + s) * HPI);
    double beta = 1.0 - (c1 * c1) / (c0 * c0);
    beta = fmin(fmax(beta, 0.0), 0.999);
    val = log1p(-beta);
  }
  l[i] = val;
  __syncthreads();
  for (int off = 1; off < 1024; off <<= 1) {
    double add = (i >= off) ? l[i - off] : 0.0;
    __syncthreads();
    l[i] += add;
    __syncthreads();
  }
  if (i < 16) {
    int tt = t[i];
    double ac = exp(l[tt]);
    double c0 = cos(((double)tt / 1000.0 + s) / (1.0 + s) * HPI);
    double c1 = cos(((double)(tt + 1) / 1000.0 + s) / (1.0 + s) * HPI);
    double beta = 1.0 - (c1 * c1) / (c0 * c0);
    beta = fmin(fmax(beta, 0.0), 0.999);
    coef[i * 4 + 0] = (float)sqrt(ac);
    coef[i * 4 + 1] = (float)sqrt(1.0 - ac);
    coef[i * 4 + 2] = (float)sqrt(beta);
  }
}

// --- fused: 3 Jacobi smoothing steps + sum-of-squares, tiled in LDS.
__global__ __launch_bounds__(256) void k_smooth3(const float* __restrict__ fu,
                                                 const float* __restrict__ fv,
                                                 float* __restrict__ dst,
                                                 float* __restrict__ norms) {
  __shared__ float sA[70 * 71];
  __shared__ float sB[70 * 71];
  __shared__ float part[4];
  int slab = blockIdx.x >> 6;
  int tile = blockIdx.x & 63;
  int tx0 = (tile & 7) << 6, ty0 = (tile >> 3) << 6;
  int b = slab & 15;
  const float* src = ((slab >> 4) ? fv : fu) + ((size_t)b << 18);
  int tid = threadIdx.x;

  for (int idx = tid; idx < 70 * 70; idx += 256) {
    int cy = idx / 70, cx = idx - cy * 70;
    int gx = (tx0 + cx - 3) & 511, gy = (ty0 + cy - 3) & 511;
    sA[cy * 71 + cx] = src[(gy << 9) + gx];
  }
  __syncthreads();
  for (int idx = tid; idx < 68 * 68; idx += 256) {
    int cy = idx / 68 + 1, cx = idx % 68 + 1;
    int o = cy * 71 + cx;
    float c = sA[o];
    sB[o] = c + 0.1f * (sA[o - 1] + sA[o + 1] + sA[o - 71] + sA[o + 71] - 4.f * c);
  }
  __syncthreads();
  for (int idx = tid; idx < 66 * 66; idx += 256) {
    int cy = idx / 66 + 2, cx = idx % 66 + 2;
    int o = cy * 71 + cx;
    float c = sB[o];
    sA[o] = c + 0.1f * (sB[o - 1] + sB[o + 1] + sB[o - 71] + sB[o + 71] - 4.f * c);
  }
  __syncthreads();
  float acc = 0.f;
  float* d = dst + ((size_t)slab << 18);
  for (int idx = tid; idx < 64 * 64; idx += 256) {
    int cy = (idx >> 6) + 3, cx = (idx & 63) + 3;
    int o = cy * 71 + cx;
    float c = sA[o];
    float v = c + 0.1f * (sA[o - 1] + sA[o + 1] + sA[o - 71] + sA[o + 71] - 4.f * c);
    d[((ty0 + cy - 3) << 9) + (tx0 + cx - 3)] = v;
    acc += v * v;
  }
  for (int off = 32; off; off >>= 1) acc += __shfl_down(acc, off, 64);
  if ((tid & 63) == 0) part[tid >> 6] = acc;
  __syncthreads();
  if (tid == 0) atomicAdd(&norms[slab], part[0] + part[1] + part[2] + part[3]);
}

#define XTLS(cb, i) (sa * x0[(cb) + (i)] + so * ns[(cb) + (i)])

// --- u*, v*: 4 pixels/thread, float4 loads
__global__ __launch_bounds__(256) void k_star(const float* __restrict__ x0,
    const float* __restrict__ ns, const float* __restrict__ fA,
    const float* __restrict__ coef, const float* __restrict__ norms,
    float* __restrict__ us, float* __restrict__ vs) {
  int gid = blockIdx.x * 256 + threadIdx.x;   // 0..BHW/4
  int x4 = (gid & 127) << 2;
  int y = (gid >> 7) & 511, b = gid >> 16;
  float sa = coef[b * 4], so = coef[b * 4 + 1], sb = coef[b * 4 + 2];
  int row = y << 9;
  int rowm = ((y + 511) & 511) << 9, rowp = ((y + 1) & 511) << 9;
  int xl = (x4 + 511) & 511, xr = (x4 + 4) & 511;
  int c0 = (b * 6) << 18, c1 = (b * 6 + 1) << 18, c2 = (b * 6 + 2) << 18;

  float4 uC = xtl4(x0, ns, c0 + row + x4, sa, so);
  float4 uU = xtl4(x0, ns, c0 + rowm + x4, sa, so);
  float4 uD = xtl4(x0, ns, c0 + rowp + x4, sa, so);
  float ulw = XTLS(c0, row + xl), urx = XTLS(c0, row + xr);
  float4 vC = xtl4(x0, ns, c1 + row + x4, sa, so);
  float4 vU = xtl4(x0, ns, c1 + rowm + x4, sa, so);
  float4 vD = xtl4(x0, ns, c1 + rowp + x4, sa, so);
  float vlw = XTLS(c1, row + xl), vrx = XTLS(c1, row + xr);
  float4 pC = xtl4(x0, ns, c2 + row + x4, sa, so);
  float4 pU = xtl4(x0, ns, c2 + rowm + x4, sa, so);
  float4 pD = xtl4(x0, ns, c2 + rowp + x4, sa, so);
  float plw = XTLS(c2, row + xl), prx = XTLS(c2, row + xr);

  float rnu = 1.f / fmaxf(sqrtf(norms[b]), 1e-12f);
  float rnv = 1.f / fmaxf(sqrtf(norms[16 + b]), 1e-12f);
  int bb = b << 18;
  float4 fu4 = ld4(fA + bb + row + x4);
  float4 fv4 = ld4(fA + ((16 + b) << 18) + row + x4);

  float ru[4], rv[4];
#pragma unroll
  for (int j = 0; j < 4; ++j) {
    float u_c = fc(uC, j), v_c = fc(vC, j);
    float u_xm = j == 0 ? ulw : fc(uC, j - 1);
    float u_xp = j == 3 ? urx : fc(uC, j + 1);
    float v_xm = j == 0 ? vlw : fc(vC, j - 1);
    float v_xp = j == 3 ? vrx : fc(vC, j + 1);
    float p_xm = j == 0 ? plw : fc(pC, j - 1);
    float p_xp = j == 3 ? prx : fc(pC, j + 1);
    float u_ym = fc(uU, j), u_yp = fc(uD, j);
    float v_ym = fc(vU, j), v_yp = fc(vD, j);
    float p_ym = fc(pU, j), p_yp = fc(pD, j);
    float adv_u = u_c * 0.5f * (u_xp - u_xm) + v_c * 0.5f * (u_yp - u_ym);
    float adv_v = u_c * 0.5f * (v_xp - v_xm) + v_c * 0.5f * (v_yp - v_ym);
    float dif_u = 0.001f * (u_xm + u_xp + u_ym + u_yp - 4.f * u_c);
    float dif_v = 0.001f * (v_xm + v_xp + v_ym + v_yp - 4.f * v_c);
    float dpx = 0.5f * (p_xp - p_xm), dpy = 0.5f * (p_yp - p_ym);
    ru[j] = u_c + 0.01f * (-adv_u + dif_u - dpx) + sb * fc(fu4, j) * rnu;
    rv[j] = v_c + 0.01f * (-adv_v + dif_v - dpy) + sb * fc(fv4, j) * rnv;
  }
  st4(us + bb + row + x4, make_float4(ru[0], ru[1], ru[2], ru[3]));
  st4(vs + bb + row + x4, make_float4(rv[0], rv[1], rv[2], rv[3]));
}

// --- row FFT of packed divergence: q = div_b + i*div_{b+8}
__global__ __launch_bounds__(256) void k_rowfft_div(const float* __restrict__ us,
    const float* __restrict__ vs, float2* __restrict__ spec) {
  __shared__ float2 buf[4 * FSTRIDE];
  __shared__ float2 tw[256];
  int tid = threadIdx.x;
  tw_init(tw, tid);
  int wave = tid >> 6, lane = tid & 63;
  int rid = (blockIdx.x << 2) + wave;   // 0..4095
  int pb = rid >> 9, y = rid & 511;
  int rym = ((y + 511) & 511) << 9, ryp = ((y + 1) & 511) << 9, ry = y << 9;
  const float* ul = us + ((size_t)pb << 18);
  const float* vl = vs + ((size_t)pb << 18);
  const float* uh = us + ((size_t)(pb + 8) << 18);
  const float* vh = vs + ((size_t)(pb + 8) << 18);
  float2* s = buf + wave * FSTRIDE;
  int xx0 = lane << 3;
  int xl = (xx0 + 511) & 511, xr = (xx0 + 8) & 511;
  float4 ulA = ld4(ul + ry + xx0), ulB = ld4(ul + ry + xx0 + 4);
  float ullw = ul[ry + xl], ulrx = ul[ry + xr];
  float4 vlU0 = ld4(vl + rym + xx0), vlU1 = ld4(vl + rym + xx0 + 4);
  float4 vlD0 = ld4(vl + ryp + xx0), vlD1 = ld4(vl + ryp + xx0 + 4);
  float4 uhA = ld4(uh + ry + xx0), uhB = ld4(uh + ry + xx0 + 4);
  float uhlw = uh[ry + xl], uhrx = uh[ry + xr];
  float4 vhU0 = ld4(vh + rym + xx0), vhU1 = ld4(vh + rym + xx0 + 4);
  float4 vhD0 = ld4(vh + ryp + xx0), vhD1 = ld4(vh + ryp + xx0 + 4);
  __syncthreads();
#pragma unroll
  for (int j = 0; j < 8; ++j) {
    float uxm = j == 0 ? ullw : fc8(ulA, ulB, j - 1);
    float uxp = j == 7 ? ulrx : fc8(ulA, ulB, j + 1);
    float dlo = 0.5f * (uxp - uxm) + 0.5f * (fc8(vlD0, vlD1, j) - fc8(vlU0, vlU1, j));
    float hxm = j == 0 ? uhlw : fc8(uhA, uhB, j - 1);
    float hxp = j == 7 ? uhrx : fc8(uhA, uhB, j + 1);
    float dhi = 0.5f * (hxp - hxm) + 0.5f * (fc8(vhD0, vhD1, j) - fc8(vhU0, vhU1, j));
    s[IDX(xx0 + j)] = make_float2(dlo, dhi);
  }
  wave_fft512(s, tw, lane, 1.f);
  float2* o = spec + ((size_t)rid << 9);
#pragma unroll
  for (int j = 0; j < 4; ++j) {
    float2 a = s[IDX(xx0 + 2 * j)], b2 = s[IDX(xx0 + 2 * j + 1)];
    st4((float*)(o + xx0 + 2 * j), make_float4(a.x, a.y, b2.x, b2.y));
  }
}

// --- fused column FFT + Poisson multiplier + column IFFT
__global__ __launch_bounds__(256) void k_poisson_mid(float2* __restrict__ spec) {
  __shared__ float2 buf[8 * FSTRIDE];
  __shared__ float2 tw[256];
  int tid = threadIdx.x;
  tw_init(tw, tid);
  int pb = blockIdx.x >> 6;
  int c0 = (blockIdx.x & 63) << 3;
  float2* sp = spec + ((size_t)pb << 18);
  int c = tid & 7, yb = tid >> 3;
  __syncthreads();
#pragma unroll
  for (int it = 0; it < 16; ++it) {
    int y = yb + (it << 5);
    buf[c * FSTRIDE + IDX(y)] = sp[((size_t)y << 9) + c0 + c];
  }
  __syncthreads();
  int wave = tid >> 6, lane = tid & 63;
  wave_fft512(buf + wave * FSTRIDE, tw, lane, 1.f);
  wave_fft512(buf + (wave + 4) * FSTRIDE, tw, lane, 1.f);
  __syncthreads();
  const float invN2 = 1.0f / 262144.0f;
#pragma unroll
  for (int it = 0; it < 16; ++it) {
    int y = yb + (it << 5);
    int cg = c0 + c;
    float fx = (cg < 256) ? (float)cg : (float)(cg - 512);
    float fy = (y < 256) ? (float)y : (float)(y - 512);
    float k2 = fmaxf(fx * fx + fy * fy, 1e-10f);
    float m = (cg == 0 && y == 0) ? 0.f : (-invN2 / (PI2SQ4 * k2));
    float2 v = buf[c * FSTRIDE + IDX(y)];
    buf[c * FSTRIDE + IDX(y)] = make_float2(v.x * m, v.y * m);
  }
  __syncthreads();
  wave_fft512(buf + wave * FSTRIDE, tw, lane, -1.f);
  wave_fft512(buf + (wave + 4) * FSTRIDE, tw, lane, -1.f);
  __syncthreads();
#pragma unroll
  for (int it = 0; it < 16; ++it) {
    int y = yb + (it << 5);
    sp[((size_t)y << 9) + c0 + c] = buf[c * FSTRIDE + IDX(y)];
  }
}

// --- row IFFT of packed Poisson solution; re->pcorr[pb], im->pcorr[pb+8]
__global__ __launch_bounds__(256) void k_rowifft_real(const float2* __restrict__ spec,
                                                      float* __restrict__ pcorr) {
  __shared__ float2 buf[4 * FSTRIDE];
  __shared__ float2 tw[256];
  int tid = threadIdx.x;
  tw_init(tw, tid);
  int wave = tid >> 6, lane = tid & 63;
  int rid = (blockIdx.x << 2) + wave;
  int pb = rid >> 9, y = rid & 511;
  const float2* srow = spec + ((size_t)rid << 9);
  float2* s = buf + wave * FSTRIDE;
  int xx0 = lane << 3;
  const float4* s4 = reinterpret_cast<const float4*>(srow + xx0);
  float4 q0 = s4[0], q1 = s4[1], q2 = s4[2], q3 = s4[3];
  __syncthreads();
  s[IDX(xx0 + 0)] = make_float2(q0.x, q0.y);
  s[IDX(xx0 + 1)] = make_float2(q0.z, q0.w);
  s[IDX(xx0 + 2)] = make_float2(q1.x, q1.y);
  s[IDX(xx0 + 3)] = make_float2(q1.z, q1.w);
  s[IDX(xx0 + 4)] = make_float2(q2.x, q2.y);
  s[IDX(xx0 + 5)] = make_float2(q2.z, q2.w);
  s[IDX(xx0 + 6)] = make_float2(q3.x, q3.y);
  s[IDX(xx0 + 7)] = make_float2(q3.z, q3.w);
  wave_fft512(s, tw, lane, -1.f);
  float* dlo = pcorr + ((size_t)pb << 18) + ((size_t)y << 9);
  float* dhi = pcorr + ((size_t)(pb + 8) << 18) + ((size_t)y << 9);
  float2 v0 = s[IDX(xx0 + 0)], v1 = s[IDX(xx0 + 1)], v2 = s[IDX(xx0 + 2)], v3 = s[IDX(xx0 + 3)];
  float2 v4 = s[IDX(xx0 + 4)], v5 = s[IDX(xx0 + 5)], v6 = s[IDX(xx0 + 6)], v7 = s[IDX(xx0 + 7)];
  st4(dlo + xx0, make_float4(v0.x, v1.x, v2.x, v3.x));
  st4(dlo + xx0 + 4, make_float4(v4.x, v5.x, v6.x, v7.x));
  st4(dhi + xx0, make_float4(v0.y, v1.y, v2.y, v3.y));
  st4(dhi + xx0 + 4, make_float4(v4.y, v5.y, v6.y, v7.y));
}

// --- fluid final outputs (channels 0,1,2): 4 pixels/thread
__global__ __launch_bounds__(256) void k_fluid_out(const float* __restrict__ x0,
    const float* __restrict__ ns, const float* __restrict__ coef,
    const float* __restrict__ us, const float* __restrict__ vs,
    const float* __restrict__ pc, float* __restrict__ out) {
  int gid = blockIdx.x * 256 + threadIdx.x;
  int x4 = (gid & 127) << 2;
  int y = (gid >> 7) & 511, b = gid >> 16;
  float sa = coef[b * 4], so = coef[b * 4 + 1];
  int row = y << 9;
  int rowm = ((y + 511) & 511) << 9, rowp = ((y + 1) & 511) << 9;
  int xl = (x4 + 511) & 511, xr = (x4 + 4) & 511;
  int bb = b << 18;
  const float* pcb = pc + bb;
  float4 pCc = ld4(pcb + row + x4);
  float4 pUu = ld4(pcb + rowm + x4);
  float4 pDd = ld4(pcb + rowp + x4);
  float plw = pcb[row + xl], prx = pcb[row + xr];
  float4 us4 = ld4(us + bb + row + x4);
  float4 vs4 = ld4(vs + bb + row + x4);
  int c2 = (b * 6 + 2) << 18;
  float4 p04 = xtl4(x0, ns, c2 + row + x4, sa, so);
  float ro0[4], ro1[4], ro2[4];
#pragma unroll
  for (int j = 0; j < 4; ++j) {
    float pxm = j == 0 ? plw : fc(pCc, j - 1);
    float pxp = j == 3 ? prx : fc(pCc, j + 1);
    ro0[j] = fc(us4, j) - 0.5f * (pxp - pxm);
    ro1[j] = fc(vs4, j) - 0.5f * (fc(pDd, j) - fc(pUu, j));
    ro2[j] = fc(p04, j) + fc(pCc, j);
  }
  st4(out + ((b * 6 + 0) << 18) + row + x4, make_float4(ro0[0], ro0[1], ro0[2], ro0[3]));
  st4(out + ((b * 6 + 1) << 18) + row + x4, make_float4(ro1[0], ro1[1], ro1[2], ro1[3]));
  st4(out + c2 + row + x4, make_float4(ro2[0], ro2[1], ro2[2], ro2[3]));
}

// --- row FFT of packed currents q = sb*(jx + i*jy)
__global__ __launch_bounds__(256) void k_rowfft_q(const float* __restrict__ jx,
    const float* __restrict__ jy, const float* __restrict__ coef,
    float2* __restrict__ spec) {
  __shared__ float2 buf[4 * FSTRIDE];
  __shared__ float2 tw[256];
  int tid = threadIdx.x;
  tw_init(tw, tid);
  int wave = tid >> 6, lane = tid & 63;
  int row = (blockIdx.x << 2) + wave;    // 0..8191
  int b = row >> 9, y = row & 511;
  float sb = coef[b * 4 + 2];
  const float* jxr = jx + ((size_t)b << 18) + ((size_t)y << 9);
  const float* jyr = jy + ((size_t)b << 18) + ((size_t)y << 9);
  float2* s = buf + wave * FSTRIDE;
  int xx0 = lane << 3;
  float4 xA = ld4(jxr + xx0), xB = ld4(jxr + xx0 + 4);
  float4 yA = ld4(jyr + xx0), yB = ld4(jyr + xx0 + 4);
  __syncthreads();
#pragma unroll
  for (int j = 0; j < 8; ++j)
    s[IDX(xx0 + j)] = make_float2(fc8(xA, xB, j) * sb, fc8(yA, yB, j) * sb);
  wave_fft512(s, tw, lane, 1.f);
  float2* o = spec + ((size_t)row << 9);
#pragma unroll
  for (int j = 0; j < 4; ++j) {
    float2 a = s[IDX(xx0 + 2 * j)], b2 = s[IDX(xx0 + 2 * j + 1)];
    st4((float*)(o + xx0 + 2 * j), make_float4(a.x, a.y, b2.x, b2.y));
  }
}

// column index for slot c (0..7) of mirror-block jj (0..63)
__device__ __forceinline__ int colof(int jj, int c) {
  int col = (c < 4) ? ((jj << 2) + c) : ((512 - (jj << 2) - 3 + (c - 4)) & 511);
  if (jj == 0 && c == 7) col = 256;
  return col;
}

// Hermitian separation + projection + recombination for one mirror pair.
__device__ __forceinline__ void proj_pair(float2* buf, int jj, int cc, int yy, int mcc) {
  int my = (512 - yy) & 511;
  float2 F1 = buf[cc * FSTRIDE + IDX(yy)];
  float2 F2 = buf[mcc * FSTRIDE + IDX(my)];
  float Jxr = 0.5f * (F1.x + F2.x), Jxi = 0.5f * (F1.y - F2.y);
  float Jyr = 0.5f * (F1.y + F2.y), Jyi = 0.5f * (F2.x - F1.x);
  int colc = colof(jj, cc);
  float fx = (colc < 256) ? (float)colc : (float)(colc - 512);
  float fy = (yy < 256) ? (float)yy : (float)(yy - 512);
  float k2 = fmaxf(fx * fx + fy * fy, 1e-10f);
  float inv = 1.0f / k2;
  float Dr = fx * Jxr + fy * Jyr, Di = fx * Jxi + fy * Jyi;
  const float invN2 = 1.0f / 262144.0f;
  float Jxr2 = (Jxr - fx * Dr * inv) * invN2, Jxi2 = (Jxi - fx * Di * inv) * invN2;
  float Jyr2 = (Jyr - fy * Dr * inv) * invN2, Jyi2 = (Jyi - fy * Di * inv) * invN2;
  buf[cc * FSTRIDE + IDX(yy)]  = make_float2(Jxr2 - Jyi2, Jxi2 + Jyr2);
  buf[mcc * FSTRIDE + IDX(my)] = make_float2(Jxr2 + Jyi2, Jyr2 - Jxi2);
}

// --- fused column FFT + Helmholtz projection + column IFFT on packed spectrum.
__global__ __launch_bounds__(256) void k_project_mid(float2* __restrict__ spec) {
  __shared__ float2 buf[8 * FSTRIDE];
  __shared__ float2 tw[256];
  int tid = threadIdx.x;
  tw_init(tw, tid);
  int bb = blockIdx.x >> 6;
  int jj = blockIdx.x & 63;
  float2* sp = spec + ((size_t)bb << 18);
  int c = tid & 7, yb = tid >> 3;
  int mycol = colof(jj, c);
  __syncthreads();
#pragma unroll
  for (int it = 0; it < 16; ++it) {
    int y = yb + (it << 5);
    buf[c * FSTRIDE + IDX(y)] = sp[((size_t)y << 9) + mycol];
  }
  __syncthreads();
  int wave = tid >> 6, lane = tid & 63;
  wave_fft512(buf + wave * FSTRIDE, tw, lane, 1.f);
  wave_fft512(buf + (wave + 4) * FSTRIDE, tw, lane, 1.f);
  __syncthreads();
#pragma unroll
  for (int it = 0; it < 8; ++it) {
    int tIdx = (it << 8) + tid;       // 0..2047
    int cc = tIdx >> 9, y = tIdx & 511;
    if (jj == 0 && cc == 0) {
      if (y > 256) {
        proj_pair(buf, 0, 7, y - 256, 7);
      } else {
        proj_pair(buf, 0, 0, y, 0);
        if (y == 0 || y == 256) proj_pair(buf, 0, 7, y, 7);
      }
    } else {
      proj_pair(buf, jj, cc, y, 7 - cc);
    }
  }
  __syncthreads();
  wave_fft512(buf + wave * FSTRIDE, tw, lane, -1.f);
  wave_fft512(buf + (wave + 4) * FSTRIDE, tw, lane, -1.f);
  __syncthreads();
#pragma unroll
  for (int it = 0; it < 16; ++it) {
    int y = yb + (it << 5);
    sp[((size_t)y << 9) + mycol] = buf[c * FSTRIDE + IDX(y)];
  }
}

// --- row IFFT of projected packed spectrum; re->jpx, im->jpy
__global__ __launch_bounds__(256) void k_rowifft_j(const float2* __restrict__ spec,
                                                   float* __restrict__ jpx,
                                                   float* __restrict__ jpy) {
  __shared__ float2 buf[4 * FSTRIDE];
  __shared__ float2 tw[256];
  int tid = threadIdx.x;
  tw_init(tw, tid);
  int wave = tid >> 6, lane = tid & 63;
  int row = (blockIdx.x << 2) + wave;
  const float2* srow = spec + ((size_t)row << 9);
  float2* s = buf + wave * FSTRIDE;
  int xx0 = lane << 3;
  const float4* s4 = reinterpret_cast<const float4*>(srow + xx0);
  float4 q0 = s4[0], q1 = s4[1], q2 = s4[2], q3 = s4[3];
  __syncthreads();
  s[IDX(xx0 + 0)] = make_float2(q0.x, q0.y);
  s[IDX(xx0 + 1)] = make_float2(q0.z, q0.w);
  s[IDX(xx0 + 2)] = make_float2(q1.x, q1.y);
  s[IDX(xx0 + 3)] = make_float2(q1.z, q1.w);
  s[IDX(xx0 + 4)] = make_float2(q2.x, q2.y);
  s[IDX(xx0 + 5)] = make_float2(q2.z, q2.w);
  s[IDX(xx0 + 6)] = make_float2(q3.x, q3.y);
  s[IDX(xx0 + 7)] = make_float2(q3.z, q3.w);
  wave_fft512(s, tw, lane, -1.f);
  float* dx = jpx + ((size_t)row << 9);
  float* dy = jpy + ((size_t)row << 9);
  float2 v0 = s[IDX(xx0 + 0)], v1 = s[IDX(xx0 + 1)], v2 = s[IDX(xx0 + 2)], v3 = s[IDX(xx0 + 3)];
  float2 v4 = s[IDX(xx0 + 4)], v5 = s[IDX(xx0 + 5)], v6 = s[IDX(xx0 + 6)], v7 = s[IDX(xx0 + 7)];
  st4(dx + xx0, make_float4(v0.x, v1.x, v2.x, v3.x));
  st4(dx + xx0 + 4, make_float4(v4.x, v5.x, v6.x, v7.x));
  st4(dy + xx0, make_float4(v0.y, v1.y, v2.y, v3.y));
  st4(dy + xx0 + 4, make_float4(v4.y, v5.y, v6.y, v7.y));
}

// --- Bz_new (channel 5): 4 pixels/thread
__global__ __launch_bounds__(256) void k_em_bz(const float* __restrict__ x0,
    const float* __restrict__ ns, const float* __restrict__ coef,
    float* __restrict__ out) {
  int gid = blockIdx.x * 256 + threadIdx.x;
  int x4 = (gid & 127) << 2;
  int y = (gid >> 7) & 511, b = gid >> 16;
  float sa = coef[b * 4], so = coef[b * 4 + 1];
  int row = y << 9;
  int rowm = ((y + 511) & 511) << 9, rowp = ((y + 1) & 511) << 9;
  int xl = (x4 + 511) & 511, xr = (x4 + 4) & 511;
  int c3 = (b * 6 + 3) << 18, c4 = (b * 6 + 4) << 18, c5 = (b * 6 + 5) << 18;
  float4 exU = xtl4(x0, ns, c3 + rowm + x4, sa, so);
  float4 exD = xtl4(x0, ns, c3 + rowp + x4, sa, so);
  float4 eyC = xtl4(x0, ns, c4 + row + x4, sa, so);
  float eylw = XTLS(c4, row + xl), eyrx = XTLS(c4, row + xr);
  float4 bzC = xtl4(x0, ns, c5 + row + x4, sa, so);
  float r[4];
#pragma unroll
  for (int j = 0; j < 4; ++j) {
    float ey_xm = j == 0 ? eylw : fc(eyC, j - 1);
    float ey_xp = j == 3 ? eyrx : fc(eyC, j + 1);
    float curl = 0.5f * (ey_xp - ey_xm) - 0.5f * (fc(exD, j) - fc(exU, j));
    r[j] = fc(bzC, j) - 0.01f * curl;   // DT/MU = 0.01
  }
  st4(out + c5 + row + x4, make_float4(r[0], r[1], r[2], r[3]));
}

// --- Ex_new, Ey_new (channels 3,4) reading Bz_new from out: 4 pixels/thread
__global__ __launch_bounds__(256) void k_em_exy(const float* __restrict__ x0,
    const float* __restrict__ ns, const float* __restrict__ coef,
    const float* __restrict__ jpx, const float* __restrict__ jpy,
    float* __restrict__ out) {
  int gid = blockIdx.x * 256 + threadIdx.x;
  int x4 = (gid & 127) << 2;
  int y = (gid >> 7) & 511, b = gid >> 16;
  float sa = coef[b * 4], so = coef[b * 4 + 1];
  int row = y << 9;
  int rowm = ((y + 511) & 511) << 9, rowp = ((y + 1) & 511) << 9;
  int xl = (x4 + 511) & 511, xr = (x4 + 4) & 511;
  int c3 = (b * 6 + 3) << 18, c4 = (b * 6 + 4) << 18, c5 = (b * 6 + 5) << 18;
  const float* bzn = out + c5;
  float4 bC = ld4(bzn + row + x4);
  float4 bU = ld4(bzn + rowm + x4);
  float4 bD = ld4(bzn + rowp + x4);
  float blw = bzn[row + xl], brx = bzn[row + xr];
  float4 ex4 = xtl4(x0, ns, c3 + row + x4, sa, so);
  float4 ey4 = xtl4(x0, ns, c4 + row + x4, sa, so);
  int bb = b << 18;
  float4 jx4 = ld4(jpx + bb + row + x4);
  float4 jy4 = ld4(jpy + bb + row + x4);
  float r3[4], r4[4];
#pragma unroll
  for (int j = 0; j < 4; ++j) {
    float bxm = j == 0 ? blw : fc(bC, j - 1);
    float bxp = j == 3 ? brx : fc(bC, j + 1);
    float ddyB = 0.5f * (fc(bD, j) - fc(bU, j));
    float ddxB = 0.5f * (bxp - bxm);
    r3[j] = fc(ex4, j) + 0.01f * ddyB - 0.01f * fc(jx4, j);  // DT/EPS = 0.01
    r4[j] = fc(ey4, j) - 0.01f * ddxB - 0.01f * fc(jy4, j);
  }
  st4(out + c3 + row + x4, make_float4(r3[0], r3[1], r3[2], r3[3]));
  st4(out + c4 + row + x4, make_float4(r4[0], r4[1], r4[2], r4[3]));
}

extern "C" void kernel_launch(void* const* d_in, const int* in_sizes, int n_in,
                              void* d_out, int out_size, void* d_ws, size_t ws_size,
                              hipStream_t stream) {
  const float* x0    = (const float*)d_in[0];
  const float* noise = (const float*)d_in[1];
  const float* f_u   = (const float*)d_in[2];
  const float* f_v   = (const float*)d_in[3];
  const float* jx    = (const float*)d_in[4];
  const float* jy    = (const float*)d_in[5];
  const int*   t     = (const int*)d_in[6];
  float* out = (float*)d_out;
  char* ws = (char*)d_ws;

  const size_t BHW = 1ull << 22;  // 16*512*512 elements
  float* coef  = (float*)ws;                 // 64 floats
  float* norms = coef + 64;                  // 32 floats
  float* fA    = (float*)(ws + 1024);        // 2*BHW (forcing; later jpx/jpy)
  float* pcorr = fA + 2 * BHW;               // BHW
  float* ustar = pcorr + BHW;                // BHW
  float* vstar = ustar + BHW;                // BHW
  float2* specP = (float2*)(vstar + BHW);    // BHW/2 complex (8 batch-pairs)
  float2* specJ = (float2*)ustar;            // BHW complex, aliases ustar+vstar
  float* jpx   = fA;                         // aliases fA (free after k_star)
  float* jpy   = fA + BHW;

  k_coef<<<1, 1024, 0, stream>>>(t, coef, norms);

  // forcing: 3 fused Jacobi smoothing steps + sumsq
  k_smooth3<<<2048, 256, 0, stream>>>(f_u, f_v, fA, norms);

  // fluid star step
  k_star<<<4096, 256, 0, stream>>>(x0, noise, fA, coef, norms, ustar, vstar);

  // Poisson solve for pressure correction (batch-pair packed)
  k_rowfft_div<<<1024, 256, 0, stream>>>(ustar, vstar, specP);
  k_poisson_mid<<<512, 256, 0, stream>>>(specP);
  k_rowifft_real<<<1024, 256, 0, stream>>>(specP, pcorr);
  k_fluid_out<<<4096, 256, 0, stream>>>(x0, noise, coef, ustar, vstar, pcorr, out);

  // divergence-free projection of currents (jx+i*jy packed)
  k_rowfft_q<<<2048, 256, 0, stream>>>(jx, jy, coef, specJ);
  k_project_mid<<<1024, 256, 0, stream>>>(specJ);
  k_rowifft_j<<<2048, 256, 0, stream>>>(specJ, jpx, jpy);

  // EM updates
  k_em_bz<<<4096, 256, 0, stream>>>(x0, noise, coef, out);
  k_em_exy<<<4096, 256, 0, stream>>>(x0, noise, coef, jpx, jpy, out);
}